// Round 5
// baseline (3048.860 us; speedup 1.0000x reference)
//
#include <hip/hip_runtime.h>

#define E_EDGES 131072
#define FIN 16
#define FF 32
#define REG_OFF (4u << 20)  // 4 MB reserved: Gaunt + CSR arrays

// ---- combo tables: 11 allowed (l1,l2,l3); blocks l=0:[0,1) l=1:[1,4) l=2:[4,9) ----
// order: (0,0,0)(0,1,1)(0,2,2)(1,0,1)(1,1,0)(1,1,2)(1,2,1)(2,0,2)(2,1,1)(2,2,0)(2,2,2)
constexpr int CIDX[11] = {0, 4, 8, 10, 12, 14, 16, 20, 22, 24, 26};
constexpr int CA0[11] = {0, 0, 0, 1, 1, 1, 1, 4, 4, 4, 4};
constexpr int CDA[11] = {1, 1, 1, 3, 3, 3, 3, 5, 5, 5, 5};
constexpr int CQ0[11] = {0, 1, 4, 0, 1, 1, 4, 0, 1, 4, 4};
constexpr int CC0[11] = {0, 1, 4, 1, 0, 4, 1, 4, 1, 0, 4};
constexpr int CDC[11] = {1, 3, 5, 3, 1, 5, 3, 5, 3, 1, 5};
constexpr int CL2[11] = {0, 1, 2, 0, 1, 1, 2, 0, 1, 2, 2};
// unpadded cumulative sizes (DA*DC): 1,3,5,9,3,15,9,25,15,5,25 -> 115
constexpr int CZ0[11] = {0, 1, 4, 9, 18, 21, 36, 45, 70, 85, 90};
// padded-to-4 offsets (sizes 4,4,8,12,4,16,12,28,16,8,28 -> 140)
constexpr int CZP[11] = {0, 4, 8, 16, 28, 32, 48, 60, 88, 104, 112};

struct P8 { float* p[8]; };

// ---------------- Gaunt tensor via exact quadrature (matches reference) -------------
__global__ void gaunt_init(float* __restrict__ G) {
    __shared__ double Ys[128][9];
    __shared__ double wq[128];
    const double ct[8] = {
        -0.9602898564975363, -0.7966664774136267, -0.5255324099163290, -0.1834346424956498,
         0.1834346424956498,  0.5255324099163290,  0.7966664774136267,  0.9602898564975363};
    const double wgt[8] = {
        0.1012285362903763, 0.2223810344533745, 0.3137066458778873, 0.3626837833783620,
        0.3626837833783620, 0.3137066458778873, 0.2223810344533745, 0.1012285362903763};
    const double PI = 3.141592653589793238462643383279502884;
    int t = threadIdx.x;
    if (t < 128) {
        int iq = t >> 4, ip = t & 15;
        double c = ct[iq];
        double s = sqrt(1.0 - c * c);
        double phi = (double)ip * (2.0 * PI / 16.0);
        double x = s * cos(phi), y = s * sin(phi), z = c;
        double* Yp = Ys[t];
        Yp[0] = 0.28209479177387814;
        Yp[1] = 0.4886025119029199 * y;
        Yp[2] = 0.4886025119029199 * z;
        Yp[3] = 0.4886025119029199 * x;
        Yp[4] = 1.0925484305920792 * x * y;
        Yp[5] = 1.0925484305920792 * y * z;
        Yp[6] = 0.31539156525252005 * (3.0 * z * z - 1.0);
        Yp[7] = 1.0925484305920792 * x * z;
        Yp[8] = 0.5462742152960396 * (x * x - y * y);
        wq[t] = wgt[iq] * (2.0 * PI / 16.0);
    }
    __syncthreads();
    for (int idx = t; idx < 729; idx += blockDim.x) {
        int a = idx / 81, b = (idx / 9) % 9, cc = idx % 9;
        double sum = 0.0;
        for (int q = 0; q < 128; ++q) sum += wq[q] * Ys[q][a] * Ys[q][b] * Ys[q][cc];
        G[idx] = (float)sum;
    }
}

// ---------------- small utility kernels ---------------------------------------------
__global__ __launch_bounds__(256) void zero_kernel(float* __restrict__ p, size_t n) {
    size_t i = (size_t)blockIdx.x * 256 + threadIdx.x;
    if (i < n) p[i] = 0.f;
}
__global__ __launch_bounds__(256) void fill_int(int* __restrict__ p, int n, int v) {
    int i = blockIdx.x * 256 + threadIdx.x;
    if (i < n) p[i] = v;
}
__global__ __launch_bounds__(256) void copy_int(const int* __restrict__ s,
                                                int* __restrict__ d, int n) {
    int i = blockIdx.x * 256 + threadIdx.x;
    if (i < n) d[i] = s[i];
}

// ---------------- CSR build ----------------------------------------------------------
__global__ __launch_bounds__(256) void csr_count(const int* __restrict__ dst,
                                                 int* __restrict__ cnt) {
    int e = blockIdx.x * 256 + threadIdx.x;
    atomicAdd(&cnt[dst[e]], 1);
}
__global__ __launch_bounds__(256) void csr_bsum(const int* __restrict__ cnt,
                                                int* __restrict__ bsum) {
    int i = blockIdx.x * 256 + threadIdx.x;
    int v = cnt[i];
#pragma unroll
    for (int off = 32; off; off >>= 1) v += __shfl_down(v, off, 64);
    __shared__ int w4[4];
    if ((threadIdx.x & 63) == 0) w4[threadIdx.x >> 6] = v;
    __syncthreads();
    if (threadIdx.x == 0) bsum[blockIdx.x] = w4[0] + w4[1] + w4[2] + w4[3];
}
__global__ void csr_scan512(int* __restrict__ bsum) {
    if (threadIdx.x == 0) {
        int run = 0;
        for (int i = 0; i < 512; ++i) { int t = bsum[i]; bsum[i] = run; run += t; }
    }
}
__global__ __launch_bounds__(256) void csr_row(const int* __restrict__ cnt,
                                               const int* __restrict__ bsum,
                                               int* __restrict__ row_start) {
    __shared__ int sd[256];
    const int i = blockIdx.x * 256 + threadIdx.x;
    const int my = cnt[i];
    sd[threadIdx.x] = my;
    __syncthreads();
    for (int off = 1; off < 256; off <<= 1) {
        int t = (threadIdx.x >= off) ? sd[threadIdx.x - off] : 0;
        __syncthreads();
        sd[threadIdx.x] += t;
        __syncthreads();
    }
    row_start[i] = bsum[blockIdx.x] + sd[threadIdx.x] - my;
    if (blockIdx.x == 511 && threadIdx.x == 255)
        row_start[E_EDGES] = bsum[511] + sd[255];
}
__global__ __launch_bounds__(256) void csr_scatter(const int* __restrict__ dst,
                                                   int* __restrict__ cursor,
                                                   int* __restrict__ eidx) {
    int e = blockIdx.x * 256 + threadIdx.x;
    int pos = atomicAdd(&cursor[dst[e]], 1);
    eidx[pos] = e;
}
// degree-sorted node permutation (wave load balance)
__global__ __launch_bounds__(256) void deg_hist(const int* __restrict__ row_start,
                                                int* __restrict__ hist) {
    int n = blockIdx.x * 256 + threadIdx.x;
    int d = row_start[n + 1] - row_start[n];
    if (d > 31) d = 31;
    atomicAdd(&hist[d], 1);
}
__global__ void deg_scan(const int* __restrict__ hist, int* __restrict__ hcur) {
    if (threadIdx.x == 0) {
        int run = 0;
        for (int i = 0; i < 32; ++i) { hcur[i] = run; run += hist[i]; }
    }
}
__global__ __launch_bounds__(256) void deg_scatter(const int* __restrict__ row_start,
                                                   int* __restrict__ hcur,
                                                   int* __restrict__ perm) {
    int n = blockIdx.x * 256 + threadIdx.x;
    int d = row_start[n + 1] - row_start[n];
    if (d > 31) d = 31;
    int pos = atomicAdd(&hcur[d], 1);
    perm[pos] = n;
}

// ---------------- embed: (E,9,16)@(16->32) into chunk-major regions ------------------
template <int CW>
__global__ __launch_bounds__(256) void embed2(
    const float* __restrict__ xin, const float* __restrict__ W0,
    const float* __restrict__ b0, P8 P) {
    constexpr int K = 32 / CW;
    int tid = threadIdx.x;
    int e = blockIdx.x * 8 + (tid >> 5);
    int f = tid & 31;
    int h = f / CW, fc = f % CW;
    float* Rh = P.p[0];
#pragma unroll
    for (int i = 1; i < K; ++i) Rh = (h == i) ? P.p[i] : Rh;
    const float* xr = xin + (size_t)e * 144;
#pragma unroll
    for (int c = 0; c < 9; ++c) {
        int l = (c == 0) ? 0 : ((c < 4) ? 1 : 2);
        const float* Wl = W0 + l * FIN * FF;
        float acc = (c == 0) ? b0[f] : 0.f;
#pragma unroll
        for (int q = 0; q < 4; ++q) {
            float4 xv = *(const float4*)&xr[c * 16 + q * 4];
            acc = fmaf(xv.x, Wl[(q * 4 + 0) * 32 + f], acc);
            acc = fmaf(xv.y, Wl[(q * 4 + 1) * 32 + f], acc);
            acc = fmaf(xv.z, Wl[(q * 4 + 2) * 32 + f], acc);
            acc = fmaf(xv.w, Wl[(q * 4 + 3) * 32 + f], acc);
        }
        Rh[((size_t)e * 9 + c) * CW + fc] = acc;
    }
}

// ---------------- per-combo einsum piece (all compile-time indexed) -----------------
template <int K>
__device__ __forceinline__ void comboP(const float* __restrict__ zrow,
                                       const float (&coef)[11], const float (&xa)[9],
                                       float (&acc)[9]) {
    constexpr int A0 = CA0[K], DA = CDA[K], C0 = CC0[K], DC = CDC[K];
    constexpr int SZ = DA * DC, N4 = (SZ + 3) / 4, ZP = CZP[K];
    float zz[N4 * 4];
    const float4* zp = (const float4*)(zrow + ZP);
#pragma unroll
    for (int j = 0; j < N4; ++j) {
        float4 v = zp[j];
        zz[4 * j + 0] = v.x; zz[4 * j + 1] = v.y; zz[4 * j + 2] = v.z; zz[4 * j + 3] = v.w;
    }
    float m[DC] = {};
#pragma unroll
    for (int a = 0; a < DA; ++a)
#pragma unroll
        for (int c = 0; c < DC; ++c) m[c] = fmaf(xa[A0 + a], zz[a * DC + c], m[c]);
#pragma unroll
    for (int c = 0; c < DC; ++c) acc[C0 + c] = fmaf(coef[K], m[c], acc[C0 + c]);
}

// ---------------- message pass, CSR pull, chunk h ------------------------------------
template <int CW>
__global__ __launch_bounds__(256) void mp_pull(
    const float* __restrict__ Xold, float* __restrict__ Xnew,
    const float* __restrict__ coords,
    const int* __restrict__ row_start, const int* __restrict__ eidx,
    const int* __restrict__ src, const int* __restrict__ perm,
    const float* __restrict__ Wm, const float* __restrict__ bm,
    const float* __restrict__ Gglob, int h) {
    constexpr int EPB = 256 / CW;
    __shared__ float gG[729];
    __shared__ int tab[115];
    __shared__ float W_s[11 * CW * 36];
    __shared__ float z_s[EPB * 140];
    const int tid = threadIdx.x;
    for (int i = tid; i < 729; i += 256) gG[i] = Gglob[i];
    for (int t = tid; t < 115; t += 256) {
        int k = 0;
#pragma unroll
        for (int kk = 1; kk < 11; ++kk) if (t >= CZ0[kk]) k = kk;
        int loc = t - CZ0[k];
        int dc = CDC[k];
        int a = loc / dc, c = loc - a * dc;
        int base = (CA0[k] + a) * 81 + CQ0[k] * 9 + (CC0[k] + c);
        tab[t] = ((CZP[k] + loc) << 12) | (CL2[k] << 10) | base;
    }
    for (int i = tid; i < 11 * CW * 32; i += 256) {
        int k = i / (CW * 32);
        int r2 = i - k * (CW * 32);
        int b = r2 / CW, fc2 = r2 - b * CW;
        W_s[(k * CW + fc2) * 36 + b] = Wm[CIDX[k] * 1024 + b * 32 + h * CW + fc2];
    }
    __syncthreads();

    const int g = tid / CW, fc = tid % CW;
    const int d = perm[blockIdx.x * EPB + g];
    const int r0 = row_start[d], r1 = row_start[d + 1];
    float acc[9];
#pragma unroll
    for (int a = 0; a < 9; ++a) acc[a] = Xold[((size_t)d * 9 + a) * CW + fc];
    float bmr[11];
#pragma unroll
    for (int k = 0; k < 11; ++k) bmr[k] = bm[CIDX[k] * 32 + h * CW + fc];
    const float ddx = coords[3 * d], ddy = coords[3 * d + 1], ddz = coords[3 * d + 2];
    float* zrow = &z_s[g * 140];

    for (int p = r0; p < r1; ++p) {
        const int e = eidx[p];
        const int s = src[e];
        float rx = ddx - coords[3 * s], ry = ddy - coords[3 * s + 1], rz = ddz - coords[3 * s + 2];
        float r = sqrtf(rx * rx + ry * ry + rz * rz + 1e-8f);
        float inv = 1.f / r;
        float ux = rx * inv, uy = ry * inv, uz = rz * inv;
        float y9[9];
        y9[0] = 0.28209479177387814f;
        y9[1] = 0.4886025119029199f * uy; y9[2] = 0.4886025119029199f * uz;
        y9[3] = 0.4886025119029199f * ux;
        y9[4] = 1.0925484305920792f * ux * uy; y9[5] = 1.0925484305920792f * uy * uz;
        y9[6] = 0.31539156525252005f * (3.f * uz * uz - 1.f);
        y9[7] = 1.0925484305920792f * ux * uz;
        y9[8] = 0.5462742152960396f * (ux * ux - uy * uy);
        // radial basis: lane owns centers b = fc + j*CW, then broadcast across group
        float radj[32 / CW];
#pragma unroll
        for (int j = 0; j < 32 / CW; ++j) {
            int b = fc + j * CW;
            float cb = (float)((double)b * (4.0 / 31.0));
            float dr = r - cb;
            radj[j] = expf(-dr * dr);
        }
        float radv[32];
#pragma unroll
        for (int b = 0; b < 32; ++b) radv[b] = __shfl(radj[b / CW], b % CW, CW);
        // z[t] = sum_b Y[Q0+b] * G[base + 9b], distributed over the group, shared in LDS
        for (int t = fc; t < 115; t += CW) {
            int u = tab[t];
            int base = u & 0x3FF;
            int l2u = (u >> 10) & 3;
            float zv;
            if (l2u == 0) {
                zv = y9[0] * gG[base];
            } else if (l2u == 1) {
                zv = y9[1] * gG[base];
                zv = fmaf(y9[2], gG[base + 9], zv);
                zv = fmaf(y9[3], gG[base + 18], zv);
            } else {
                zv = y9[4] * gG[base];
                zv = fmaf(y9[5], gG[base + 9], zv);
                zv = fmaf(y9[6], gG[base + 18], zv);
                zv = fmaf(y9[7], gG[base + 27], zv);
                zv = fmaf(y9[8], gG[base + 36], zv);
            }
            zrow[u >> 12] = zv;
        }
        asm volatile("s_waitcnt lgkmcnt(0)" ::: "memory");
        // gather source features
        float xa[9];
#pragma unroll
        for (int a = 0; a < 9; ++a) xa[a] = Xold[((size_t)s * 9 + a) * CW + fc];
        // coef[k] = bm + rad @ W (W from LDS, b128, conflict-free via 36-pad)
        float coef[11];
#pragma unroll
        for (int k = 0; k < 11; ++k) {
            float cc = bmr[k];
            const float4* wp = (const float4*)&W_s[(k * CW + fc) * 36];
#pragma unroll
            for (int b4 = 0; b4 < 8; ++b4) {
                float4 w = wp[b4];
                cc = fmaf(radv[b4 * 4 + 0], w.x, cc);
                cc = fmaf(radv[b4 * 4 + 1], w.y, cc);
                cc = fmaf(radv[b4 * 4 + 2], w.z, cc);
                cc = fmaf(radv[b4 * 4 + 3], w.w, cc);
            }
            coef[k] = cc;
        }
        // einsum + accumulate
        comboP<0>(zrow, coef, xa, acc);
        comboP<1>(zrow, coef, xa, acc);
        comboP<2>(zrow, coef, xa, acc);
        comboP<3>(zrow, coef, xa, acc);
        comboP<4>(zrow, coef, xa, acc);
        comboP<5>(zrow, coef, xa, acc);
        comboP<6>(zrow, coef, xa, acc);
        comboP<7>(zrow, coef, xa, acc);
        comboP<8>(zrow, coef, xa, acc);
        comboP<9>(zrow, coef, xa, acc);
        comboP<10>(zrow, coef, xa, acc);
    }
#pragma unroll
    for (int a = 0; a < 9; ++a) Xnew[((size_t)d * 9 + a) * CW + fc] = acc[a];
}

// ---------------- final: dense(32->32) + gate + dense(32->1) ------------------------
template <int CW>
__global__ __launch_bounds__(256) void final3(
    P8 P, const float* __restrict__ W1, const float* __restrict__ b1,
    const float* __restrict__ W2, const float* __restrict__ b2,
    float* __restrict__ out) {
    constexpr int K = 32 / CW;
    __shared__ float Xs[8 * 9 * 36];
    const int tid = threadIdx.x;
    const int g = tid >> 5, f = tid & 31;
    const float* Rh = P.p[0];
#pragma unroll
    for (int i = 1; i < K; ++i) Rh = ((f / CW) == i) ? P.p[i] : Rh;
    const int fc = f % CW;
    float w1r[3][32];
#pragma unroll
    for (int l = 0; l < 3; ++l)
#pragma unroll
        for (int q = 0; q < 32; ++q) w1r[l][q] = W1[(l * 32 + q) * 32 + f];
    float w2r[3];
#pragma unroll
    for (int l = 0; l < 3; ++l) w2r[l] = W2[l * 32 + f];
    const float b1f = b1[f], b20 = b2[0];
    for (int bb = 0; bb < 16; ++bb) {
        const int e = blockIdx.x * 128 + bb * 8 + g;
        __syncthreads();
#pragma unroll
        for (int c = 0; c < 9; ++c)
            Xs[(g * 9 + c) * 36 + f] = Rh[((size_t)e * 9 + c) * CW + fc];
        __syncthreads();
        float t[9];
#pragma unroll
        for (int c = 0; c < 9; ++c) {
            const int l = (c == 0) ? 0 : ((c < 4) ? 1 : 2);
            float acc = (c == 0) ? b1f : 0.f;
            const float4* xp = (const float4*)&Xs[(g * 9 + c) * 36];
#pragma unroll
            for (int q = 0; q < 8; ++q) {
                float4 xv = xp[q];
                acc = fmaf(xv.x, w1r[l][q * 4 + 0], acc);
                acc = fmaf(xv.y, w1r[l][q * 4 + 1], acc);
                acc = fmaf(xv.z, w1r[l][q * 4 + 2], acc);
                acc = fmaf(xv.w, w1r[l][q * 4 + 3], acc);
            }
            t[c] = acc;
        }
        const float gate = (t[0] > 0.f) ? 1.f : 0.f;
#pragma unroll
        for (int c = 0; c < 9; ++c) {
            const int l = (c == 0) ? 0 : ((c < 4) ? 1 : 2);
            float v = t[c] * gate * w2r[l];
#pragma unroll
            for (int off = 16; off; off >>= 1) v += __shfl_xor(v, off, 32);
            if (f == 0) out[(size_t)e * 9 + c] = v + ((c == 0) ? b20 : 0.f);
        }
    }
}

// ---------------- driver -------------------------------------------------------------
template <int CW>
static void run_all(const float* x_dftb, const float* coords, const int* dst,
                    const int* src, const float* W0, const float* b0,
                    const float* Wmp, const float* bmp, const float* W1,
                    const float* b1, const float* W2, const float* b2,
                    float* out, char* ws, hipStream_t stream) {
    constexpr int K = 32 / CW;
    constexpr int EPB = 256 / CW;
    size_t sliceB = (size_t)E_EDGES * 9 * CW * sizeof(float);
    float* G = (float*)ws;
    int* row_start = (int*)(ws + 4096);
    int* eidx = (int*)(ws + 4096 + 640 * 1024);
    int* cnt = (int*)(ws + 4096 + 2 * 640 * 1024);
    int* cursor = (int*)(ws + 4096 + 3 * 640 * 1024);
    int* perm = (int*)(ws + 4096 + 4 * 640 * 1024);
    int* bsum = (int*)(ws + 4096 + 5 * 640 * 1024);
    int* hist = (int*)(ws + 4096 + 5 * 640 * 1024 + 4096);
    int* hcur = (int*)(ws + 4096 + 5 * 640 * 1024 + 4096 + 256);

    float* reg[K + 1];
    for (int i = 0; i <= K; ++i) reg[i] = (float*)(ws + REG_OFF + (size_t)i * sliceB);
    int cur[K];
    for (int i = 0; i < K; ++i) cur[i] = i;
    int spare = K;

    const int EB = E_EDGES / 256;  // 512
    gaunt_init<<<1, 256, 0, stream>>>(G);
    // CSR by dst
    fill_int<<<EB, 256, 0, stream>>>(cnt, E_EDGES, 0);
    csr_count<<<EB, 256, 0, stream>>>(dst, cnt);
    csr_bsum<<<EB, 256, 0, stream>>>(cnt, bsum);
    csr_scan512<<<1, 64, 0, stream>>>(bsum);
    csr_row<<<EB, 256, 0, stream>>>(cnt, bsum, row_start);
    copy_int<<<EB, 256, 0, stream>>>(row_start, cursor, E_EDGES);
    csr_scatter<<<EB, 256, 0, stream>>>(dst, cursor, eidx);
    // degree-sorted permutation
    fill_int<<<1, 256, 0, stream>>>(hist, 64, 0);
    deg_hist<<<EB, 256, 0, stream>>>(row_start, hist);
    deg_scan<<<1, 64, 0, stream>>>(hist, hcur);
    deg_scatter<<<EB, 256, 0, stream>>>(row_start, hcur, perm);
    // embed
    P8 Pe;
    for (int i = 0; i < 8; ++i) Pe.p[i] = reg[(i < K) ? cur[i] : 0];
    embed2<CW><<<E_EDGES / 8, 256, 0, stream>>>(x_dftb, W0, b0, Pe);
    // 2 message-passing steps, K chunks each
    for (int step = 0; step < 2; ++step) {
        const float* Ws = Wmp + step * 27648;
        const float* bs = bmp + step * 864;
        for (int h = 0; h < K; ++h) {
            mp_pull<CW><<<E_EDGES / EPB, 256, 0, stream>>>(
                reg[cur[h]], reg[spare], coords, row_start, eidx, src, perm, Ws, bs, G, h);
            int tmp = cur[h]; cur[h] = spare; spare = tmp;
        }
    }
    P8 Pf;
    for (int i = 0; i < 8; ++i) Pf.p[i] = reg[(i < K) ? cur[i] : 0];
    final3<CW><<<1024, 256, 0, stream>>>(Pf, W1, b1, W2, b2, out);
}

extern "C" void kernel_launch(void* const* d_in, const int* in_sizes, int n_in,
                              void* d_out, int out_size, void* d_ws, size_t ws_size,
                              hipStream_t stream) {
    const float* x_dftb = (const float*)d_in[0];
    const float* coords = (const float*)d_in[1];
    const int* dst = (const int*)d_in[2];
    const int* src = (const int*)d_in[3];
    const float* W0 = (const float*)d_in[4];
    const float* b0 = (const float*)d_in[5];
    const float* Wmp = (const float*)d_in[6];
    const float* bmp = (const float*)d_in[7];
    const float* W1 = (const float*)d_in[8];
    const float* b1 = (const float*)d_in[9];
    const float* W2 = (const float*)d_in[10];
    const float* b2 = (const float*)d_in[11];
    float* out = (float*)d_out;
    char* ws = (char*)d_ws;

    size_t slice8 = (size_t)E_EDGES * 9 * 8 * sizeof(float);
    size_t slice4 = (size_t)E_EDGES * 9 * 4 * sizeof(float);
    size_t need8 = REG_OFF + 5 * slice8;   // ~193 MB
    size_t need4 = REG_OFF + 9 * slice4;   // ~174 MB
    if (ws_size >= need8) {
        run_all<8>(x_dftb, coords, dst, src, W0, b0, Wmp, bmp, W1, b1, W2, b2, out, ws, stream);
    } else if (ws_size >= need4) {
        run_all<4>(x_dftb, coords, dst, src, W0, b0, Wmp, bmp, W1, b1, W2, b2, out, ws, stream);
    } else {
        zero_kernel<<<(out_size + 255) / 256, 256, 0, stream>>>(out, (size_t)out_size);
    }
}

// Round 6
// 1299.474 us; speedup vs baseline: 2.3462x; 2.3462x over previous
//
#include <hip/hip_runtime.h>

#define E_EDGES 131072
#define FIN 16
#define FF 32
#define REG_OFF (4u << 20)  // 4 MB reserved: Gaunt + CSR + sort arrays

// ---- combo tables: 11 allowed (l1,l2,l3); blocks l=0:[0,1) l=1:[1,4) l=2:[4,9) ----
constexpr int CIDX[11] = {0, 4, 8, 10, 12, 14, 16, 20, 22, 24, 26};
constexpr int CA0[11] = {0, 0, 0, 1, 1, 1, 1, 4, 4, 4, 4};
constexpr int CDA[11] = {1, 1, 1, 3, 3, 3, 3, 5, 5, 5, 5};
constexpr int CQ0[11] = {0, 1, 4, 0, 1, 1, 4, 0, 1, 4, 4};
constexpr int CC0[11] = {0, 1, 4, 1, 0, 4, 1, 4, 1, 0, 4};
constexpr int CDC[11] = {1, 3, 5, 3, 1, 5, 3, 5, 3, 1, 5};
constexpr int CL2[11] = {0, 1, 2, 0, 1, 1, 2, 0, 1, 2, 2};
constexpr int CZ0[11] = {0, 1, 4, 9, 18, 21, 36, 45, 70, 85, 90};   // unpadded cum, 115
constexpr int CZP[11] = {0, 4, 8, 16, 28, 32, 48, 60, 88, 104, 112}; // pad4 offsets, 140

struct P8 { float* p[8]; };

// ---------------- Gaunt tensor via exact quadrature (matches reference) -------------
__global__ void gaunt_init(float* __restrict__ G) {
    __shared__ double Ys[128][9];
    __shared__ double wq[128];
    const double ct[8] = {
        -0.9602898564975363, -0.7966664774136267, -0.5255324099163290, -0.1834346424956498,
         0.1834346424956498,  0.5255324099163290,  0.7966664774136267,  0.9602898564975363};
    const double wgt[8] = {
        0.1012285362903763, 0.2223810344533745, 0.3137066458778873, 0.3626837833783620,
        0.3626837833783620, 0.3137066458778873, 0.2223810344533745, 0.1012285362903763};
    const double PI = 3.141592653589793238462643383279502884;
    int t = threadIdx.x;
    if (t < 128) {
        int iq = t >> 4, ip = t & 15;
        double c = ct[iq];
        double s = sqrt(1.0 - c * c);
        double phi = (double)ip * (2.0 * PI / 16.0);
        double x = s * cos(phi), y = s * sin(phi), z = c;
        double* Yp = Ys[t];
        Yp[0] = 0.28209479177387814;
        Yp[1] = 0.4886025119029199 * y;
        Yp[2] = 0.4886025119029199 * z;
        Yp[3] = 0.4886025119029199 * x;
        Yp[4] = 1.0925484305920792 * x * y;
        Yp[5] = 1.0925484305920792 * y * z;
        Yp[6] = 0.31539156525252005 * (3.0 * z * z - 1.0);
        Yp[7] = 1.0925484305920792 * x * z;
        Yp[8] = 0.5462742152960396 * (x * x - y * y);
        wq[t] = wgt[iq] * (2.0 * PI / 16.0);
    }
    __syncthreads();
    for (int idx = t; idx < 729; idx += blockDim.x) {
        int a = idx / 81, b = (idx / 9) % 9, cc = idx % 9;
        double sum = 0.0;
        for (int q = 0; q < 128; ++q) sum += wq[q] * Ys[q][a] * Ys[q][b] * Ys[q][cc];
        G[idx] = (float)sum;
    }
}

// ---------------- small utility kernels ---------------------------------------------
__global__ __launch_bounds__(256) void zero_kernel(float* __restrict__ p, size_t n) {
    size_t i = (size_t)blockIdx.x * 256 + threadIdx.x;
    if (i < n) p[i] = 0.f;
}
__global__ __launch_bounds__(256) void fill_int(int* __restrict__ p, int n, int v) {
    int i = blockIdx.x * 256 + threadIdx.x;
    if (i < n) p[i] = v;
}
__global__ __launch_bounds__(256) void copy_int(const int* __restrict__ s,
                                                int* __restrict__ d, int n) {
    int i = blockIdx.x * 256 + threadIdx.x;
    if (i < n) d[i] = s[i];
}

// ---------------- CSR build ----------------------------------------------------------
__global__ __launch_bounds__(256) void csr_count(const int* __restrict__ dst,
                                                 int* __restrict__ cnt) {
    int e = blockIdx.x * 256 + threadIdx.x;
    atomicAdd(&cnt[dst[e]], 1);   // 131072 spread addresses: low contention
}
__global__ __launch_bounds__(256) void csr_bsum(const int* __restrict__ cnt,
                                                int* __restrict__ bsum) {
    int i = blockIdx.x * 256 + threadIdx.x;
    int v = cnt[i];
#pragma unroll
    for (int off = 32; off; off >>= 1) v += __shfl_down(v, off, 64);
    __shared__ int w4[4];
    if ((threadIdx.x & 63) == 0) w4[threadIdx.x >> 6] = v;
    __syncthreads();
    if (threadIdx.x == 0) bsum[blockIdx.x] = w4[0] + w4[1] + w4[2] + w4[3];
}
// exclusive scan of 512 ints, one wave, shuffle-based
__global__ void scan512_wave(int* __restrict__ b) {
    int lane = threadIdx.x;  // 64 threads
    int run = 0;
    for (int c = 0; c < 8; ++c) {
        int v = b[c * 64 + lane];
        int s = v;
#pragma unroll
        for (int off = 1; off < 64; off <<= 1) {
            int t = __shfl_up(s, off, 64);
            if (lane >= off) s += t;
        }
        b[c * 64 + lane] = run + s - v;
        run += __shfl(s, 63, 64);
    }
}
__global__ __launch_bounds__(256) void csr_row(const int* __restrict__ cnt,
                                               const int* __restrict__ bsum,
                                               int* __restrict__ row_start) {
    __shared__ int sd[256];
    const int i = blockIdx.x * 256 + threadIdx.x;
    const int my = cnt[i];
    sd[threadIdx.x] = my;
    __syncthreads();
    for (int off = 1; off < 256; off <<= 1) {
        int t = (threadIdx.x >= off) ? sd[threadIdx.x - off] : 0;
        __syncthreads();
        sd[threadIdx.x] += t;
        __syncthreads();
    }
    row_start[i] = bsum[blockIdx.x] + sd[threadIdx.x] - my;
    if (blockIdx.x == 511 && threadIdx.x == 255)
        row_start[E_EDGES] = bsum[511] + sd[255];
}
__global__ __launch_bounds__(256) void csr_scatter(const int* __restrict__ dst,
                                                   int* __restrict__ cursor,
                                                   int* __restrict__ eidx) {
    int e = blockIdx.x * 256 + threadIdx.x;
    int pos = atomicAdd(&cursor[dst[e]], 1);  // spread addresses: fine
    eidx[pos] = e;
}

// ---------------- degree counting-sort (no contended global atomics) ----------------
__global__ __launch_bounds__(256) void sort1(const int* __restrict__ cnt,
                                             int* __restrict__ blockhist) {
    __shared__ int h[32];
    if (threadIdx.x < 32) h[threadIdx.x] = 0;
    __syncthreads();
    int n = blockIdx.x * 256 + threadIdx.x;
    int d = cnt[n]; if (d > 31) d = 31;
    atomicAdd(&h[d], 1);  // LDS atomic, cheap
    __syncthreads();
    if (threadIdx.x < 32) blockhist[threadIdx.x * 512 + blockIdx.x] = h[threadIdx.x];
}
// per-bin exclusive scan over 512 blocks + bin-base offsets; 1 block, 1024 threads
__global__ __launch_bounds__(1024) void sort2(int* __restrict__ blockhist) {
    __shared__ int tot[32];
    int wv = threadIdx.x >> 6, lane = threadIdx.x & 63;  // 16 waves, 2 bins each
#pragma unroll
    for (int bi = 0; bi < 2; ++bi) {
        int bin = wv * 2 + bi;
        int run = 0;
        for (int c = 0; c < 8; ++c) {
            int v = blockhist[bin * 512 + c * 64 + lane];
            int s = v;
#pragma unroll
            for (int off = 1; off < 64; off <<= 1) {
                int t = __shfl_up(s, off, 64);
                if (lane >= off) s += t;
            }
            blockhist[bin * 512 + c * 64 + lane] = run + s - v;
            run += __shfl(s, 63, 64);
        }
        if (lane == 0) tot[bin] = run;
    }
    __syncthreads();
    if (threadIdx.x == 0) {
        int run = 0;
        for (int i = 0; i < 32; ++i) { int t = tot[i]; tot[i] = run; run += t; }
    }
    __syncthreads();
#pragma unroll
    for (int bi = 0; bi < 2; ++bi) {
        int bin = wv * 2 + bi;
        int base = tot[bin];
        for (int c = 0; c < 8; ++c) blockhist[bin * 512 + c * 64 + lane] += base;
    }
}
__global__ __launch_bounds__(256) void sort3(const int* __restrict__ cnt,
                                             const int* __restrict__ blockhist,
                                             int* __restrict__ perm) {
    __shared__ int cur[32];
    if (threadIdx.x < 32) cur[threadIdx.x] = blockhist[threadIdx.x * 512 + blockIdx.x];
    __syncthreads();
    int n = blockIdx.x * 256 + threadIdx.x;
    int d = cnt[n]; if (d > 31) d = 31;
    int pos = atomicAdd(&cur[d], 1);  // LDS atomic, cheap
    perm[pos] = n;
}

// ---------------- embed: (E,9,16)@(16->32) into chunk-major regions ------------------
template <int CW>
__global__ __launch_bounds__(256) void embed2(
    const float* __restrict__ xin, const float* __restrict__ W0,
    const float* __restrict__ b0, P8 P) {
    constexpr int K = 32 / CW;
    int tid = threadIdx.x;
    int e = blockIdx.x * 8 + (tid >> 5);
    int f = tid & 31;
    int h = f / CW, fc = f % CW;
    float* Rh = P.p[0];
#pragma unroll
    for (int i = 1; i < K; ++i) Rh = (h == i) ? P.p[i] : Rh;
    const float* xr = xin + (size_t)e * 144;
#pragma unroll
    for (int c = 0; c < 9; ++c) {
        int l = (c == 0) ? 0 : ((c < 4) ? 1 : 2);
        const float* Wl = W0 + l * FIN * FF;
        float acc = (c == 0) ? b0[f] : 0.f;
#pragma unroll
        for (int q = 0; q < 4; ++q) {
            float4 xv = *(const float4*)&xr[c * 16 + q * 4];
            acc = fmaf(xv.x, Wl[(q * 4 + 0) * 32 + f], acc);
            acc = fmaf(xv.y, Wl[(q * 4 + 1) * 32 + f], acc);
            acc = fmaf(xv.z, Wl[(q * 4 + 2) * 32 + f], acc);
            acc = fmaf(xv.w, Wl[(q * 4 + 3) * 32 + f], acc);
        }
        Rh[((size_t)e * 9 + c) * CW + fc] = acc;
    }
}

// ---------------- per-combo einsum piece (all compile-time indexed) -----------------
template <int K>
__device__ __forceinline__ void comboP(const float* __restrict__ zrow,
                                       const float (&coef)[11], const float (&xa)[9],
                                       float (&acc)[9]) {
    constexpr int A0 = CA0[K], DA = CDA[K], C0 = CC0[K], DC = CDC[K];
    constexpr int SZ = DA * DC, N4 = (SZ + 3) / 4, ZP = CZP[K];
    float zz[N4 * 4];
    const float4* zp = (const float4*)(zrow + ZP);
#pragma unroll
    for (int j = 0; j < N4; ++j) {
        float4 v = zp[j];
        zz[4 * j + 0] = v.x; zz[4 * j + 1] = v.y; zz[4 * j + 2] = v.z; zz[4 * j + 3] = v.w;
    }
    float m[DC] = {};
#pragma unroll
    for (int a = 0; a < DA; ++a)
#pragma unroll
        for (int c = 0; c < DC; ++c) m[c] = fmaf(xa[A0 + a], zz[a * DC + c], m[c]);
#pragma unroll
    for (int c = 0; c < DC; ++c) acc[C0 + c] = fmaf(coef[K], m[c], acc[C0 + c]);
}

// ---------------- message pass, CSR pull, chunk h ------------------------------------
template <int CW>
__global__ __launch_bounds__(256) void mp_pull(
    const float* __restrict__ Xold, float* __restrict__ Xnew,
    const float* __restrict__ coords,
    const int* __restrict__ row_start, const int* __restrict__ eidx,
    const int* __restrict__ src, const int* __restrict__ perm,
    const float* __restrict__ Wm, const float* __restrict__ bm,
    const float* __restrict__ Gglob, int h) {
    constexpr int EPB = 256 / CW;
    __shared__ float gG[729];
    __shared__ int tab[115];
    __shared__ float W_s[11 * CW * 36];
    __shared__ float z_s[EPB * 140];
    const int tid = threadIdx.x;
    for (int i = tid; i < 729; i += 256) gG[i] = Gglob[i];
    for (int t = tid; t < 115; t += 256) {
        int k = 0;
#pragma unroll
        for (int kk = 1; kk < 11; ++kk) if (t >= CZ0[kk]) k = kk;
        int loc = t - CZ0[k];
        int dc = CDC[k];
        int a = loc / dc, c = loc - a * dc;
        int base = (CA0[k] + a) * 81 + CQ0[k] * 9 + (CC0[k] + c);
        tab[t] = ((CZP[k] + loc) << 12) | (CL2[k] << 10) | base;
    }
    for (int i = tid; i < 11 * CW * 32; i += 256) {
        int k = i / (CW * 32);
        int r2 = i - k * (CW * 32);
        int b = r2 / CW, fc2 = r2 - b * CW;
        W_s[(k * CW + fc2) * 36 + b] = Wm[CIDX[k] * 1024 + b * 32 + h * CW + fc2];
    }
    __syncthreads();

    const int g = tid / CW, fc = tid % CW;
    const int d = perm[blockIdx.x * EPB + g];
    const int r0 = row_start[d], r1 = row_start[d + 1];
    float acc[9];
#pragma unroll
    for (int a = 0; a < 9; ++a) acc[a] = Xold[((size_t)d * 9 + a) * CW + fc];
    float bmr[11];
#pragma unroll
    for (int k = 0; k < 11; ++k) bmr[k] = bm[CIDX[k] * 32 + h * CW + fc];
    const float ddx = coords[3 * d], ddy = coords[3 * d + 1], ddz = coords[3 * d + 2];
    float* zrow = &z_s[g * 140];

    for (int p = r0; p < r1; ++p) {
        const int e = eidx[p];
        const int s = src[e];
        // issue the 9 gather loads early: their latency hides under geometry+z VALU
        float xa[9];
#pragma unroll
        for (int a = 0; a < 9; ++a) xa[a] = Xold[((size_t)s * 9 + a) * CW + fc];
        float rx = ddx - coords[3 * s], ry = ddy - coords[3 * s + 1], rz = ddz - coords[3 * s + 2];
        float r = sqrtf(rx * rx + ry * ry + rz * rz + 1e-8f);
        float inv = 1.f / r;
        float ux = rx * inv, uy = ry * inv, uz = rz * inv;
        float y9[9];
        y9[0] = 0.28209479177387814f;
        y9[1] = 0.4886025119029199f * uy; y9[2] = 0.4886025119029199f * uz;
        y9[3] = 0.4886025119029199f * ux;
        y9[4] = 1.0925484305920792f * ux * uy; y9[5] = 1.0925484305920792f * uy * uz;
        y9[6] = 0.31539156525252005f * (3.f * uz * uz - 1.f);
        y9[7] = 1.0925484305920792f * ux * uz;
        y9[8] = 0.5462742152960396f * (ux * ux - uy * uy);
        // radial basis: lane owns centers b = fc + j*CW, broadcast via shuffle
        float radj[32 / CW];
#pragma unroll
        for (int j = 0; j < 32 / CW; ++j) {
            int b = fc + j * CW;
            float cb = (float)((double)b * (4.0 / 31.0));
            float dr = r - cb;
            radj[j] = expf(-dr * dr);
        }
        float radv[32];
#pragma unroll
        for (int b = 0; b < 32; ++b) radv[b] = __shfl(radj[b / CW], b % CW, CW);
        // z[t] = sum_b Y[Q0+b] * G[base + 9b], distributed over group, shared in LDS
        for (int t = fc; t < 115; t += CW) {
            int u = tab[t];
            int base = u & 0x3FF;
            int l2u = (u >> 10) & 3;
            float zv;
            if (l2u == 0) {
                zv = y9[0] * gG[base];
            } else if (l2u == 1) {
                zv = y9[1] * gG[base];
                zv = fmaf(y9[2], gG[base + 9], zv);
                zv = fmaf(y9[3], gG[base + 18], zv);
            } else {
                zv = y9[4] * gG[base];
                zv = fmaf(y9[5], gG[base + 9], zv);
                zv = fmaf(y9[6], gG[base + 18], zv);
                zv = fmaf(y9[7], gG[base + 27], zv);
                zv = fmaf(y9[8], gG[base + 36], zv);
            }
            zrow[u >> 12] = zv;
        }
        asm volatile("s_waitcnt lgkmcnt(0)" ::: "memory");
        // coef[k] = bm + rad @ W  (W from LDS, b128, conflict-free via 36-pad)
        float coef[11];
#pragma unroll
        for (int k = 0; k < 11; ++k) {
            float cc = bmr[k];
            const float4* wp = (const float4*)&W_s[(k * CW + fc) * 36];
#pragma unroll
            for (int b4 = 0; b4 < 8; ++b4) {
                float4 w = wp[b4];
                cc = fmaf(radv[b4 * 4 + 0], w.x, cc);
                cc = fmaf(radv[b4 * 4 + 1], w.y, cc);
                cc = fmaf(radv[b4 * 4 + 2], w.z, cc);
                cc = fmaf(radv[b4 * 4 + 3], w.w, cc);
            }
            coef[k] = cc;
        }
        comboP<0>(zrow, coef, xa, acc);
        comboP<1>(zrow, coef, xa, acc);
        comboP<2>(zrow, coef, xa, acc);
        comboP<3>(zrow, coef, xa, acc);
        comboP<4>(zrow, coef, xa, acc);
        comboP<5>(zrow, coef, xa, acc);
        comboP<6>(zrow, coef, xa, acc);
        comboP<7>(zrow, coef, xa, acc);
        comboP<8>(zrow, coef, xa, acc);
        comboP<9>(zrow, coef, xa, acc);
        comboP<10>(zrow, coef, xa, acc);
    }
#pragma unroll
    for (int a = 0; a < 9; ++a) Xnew[((size_t)d * 9 + a) * CW + fc] = acc[a];
}

// ---------------- final: dense(32->32) + gate + dense(32->1) ------------------------
template <int CW>
__global__ __launch_bounds__(256) void final3(
    P8 P, const float* __restrict__ W1, const float* __restrict__ b1,
    const float* __restrict__ W2, const float* __restrict__ b2,
    float* __restrict__ out) {
    constexpr int K = 32 / CW;
    __shared__ float Xs[8 * 9 * 36];
    const int tid = threadIdx.x;
    const int g = tid >> 5, f = tid & 31;
    const float* Rh = P.p[0];
#pragma unroll
    for (int i = 1; i < K; ++i) Rh = ((f / CW) == i) ? P.p[i] : Rh;
    const int fc = f % CW;
    float w1r[3][32];
#pragma unroll
    for (int l = 0; l < 3; ++l)
#pragma unroll
        for (int q = 0; q < 32; ++q) w1r[l][q] = W1[(l * 32 + q) * 32 + f];
    float w2r[3];
#pragma unroll
    for (int l = 0; l < 3; ++l) w2r[l] = W2[l * 32 + f];
    const float b1f = b1[f], b20 = b2[0];
    for (int bb = 0; bb < 16; ++bb) {
        const int e = blockIdx.x * 128 + bb * 8 + g;
        __syncthreads();
#pragma unroll
        for (int c = 0; c < 9; ++c)
            Xs[(g * 9 + c) * 36 + f] = Rh[((size_t)e * 9 + c) * CW + fc];
        __syncthreads();
        float t[9];
#pragma unroll
        for (int c = 0; c < 9; ++c) {
            const int l = (c == 0) ? 0 : ((c < 4) ? 1 : 2);
            float acc = (c == 0) ? b1f : 0.f;
            const float4* xp = (const float4*)&Xs[(g * 9 + c) * 36];
#pragma unroll
            for (int q = 0; q < 8; ++q) {
                float4 xv = xp[q];
                acc = fmaf(xv.x, w1r[l][q * 4 + 0], acc);
                acc = fmaf(xv.y, w1r[l][q * 4 + 1], acc);
                acc = fmaf(xv.z, w1r[l][q * 4 + 2], acc);
                acc = fmaf(xv.w, w1r[l][q * 4 + 3], acc);
            }
            t[c] = acc;
        }
        const float gate = (t[0] > 0.f) ? 1.f : 0.f;
#pragma unroll
        for (int c = 0; c < 9; ++c) {
            const int l = (c == 0) ? 0 : ((c < 4) ? 1 : 2);
            float v = t[c] * gate * w2r[l];
#pragma unroll
            for (int off = 16; off; off >>= 1) v += __shfl_xor(v, off, 32);
            if (f == 0) out[(size_t)e * 9 + c] = v + ((c == 0) ? b20 : 0.f);
        }
    }
}

// ---------------- driver -------------------------------------------------------------
template <int CW>
static void run_all(const float* x_dftb, const float* coords, const int* dst,
                    const int* src, const float* W0, const float* b0,
                    const float* Wmp, const float* bmp, const float* W1,
                    const float* b1, const float* W2, const float* b2,
                    float* out, char* ws, hipStream_t stream) {
    constexpr int K = 32 / CW;
    constexpr int EPB = 256 / CW;
    size_t sliceB = (size_t)E_EDGES * 9 * CW * sizeof(float);
    float* G = (float*)ws;
    int* row_start = (int*)(ws + 4096);
    int* eidx = (int*)(ws + 4096 + 1 * 640 * 1024);
    int* cnt = (int*)(ws + 4096 + 2 * 640 * 1024);
    int* cursor = (int*)(ws + 4096 + 3 * 640 * 1024);
    int* perm = (int*)(ws + 4096 + 4 * 640 * 1024);
    int* bsum = (int*)(ws + 4096 + 5 * 640 * 1024);          // 512 ints
    int* blockhist = (int*)(ws + 4096 + 5 * 640 * 1024 + 64 * 1024);  // 32*512 ints

    float* reg[K + 1];
    for (int i = 0; i <= K; ++i) reg[i] = (float*)(ws + REG_OFF + (size_t)i * sliceB);
    int cur[K];
    for (int i = 0; i < K; ++i) cur[i] = i;
    int spare = K;

    const int EB = E_EDGES / 256;  // 512
    gaunt_init<<<1, 256, 0, stream>>>(G);
    // CSR by dst
    fill_int<<<EB, 256, 0, stream>>>(cnt, E_EDGES, 0);
    csr_count<<<EB, 256, 0, stream>>>(dst, cnt);
    csr_bsum<<<EB, 256, 0, stream>>>(cnt, bsum);
    scan512_wave<<<1, 64, 0, stream>>>(bsum);
    csr_row<<<EB, 256, 0, stream>>>(cnt, bsum, row_start);
    copy_int<<<EB, 256, 0, stream>>>(row_start, cursor, E_EDGES);
    csr_scatter<<<EB, 256, 0, stream>>>(dst, cursor, eidx);
    // degree counting-sort -> perm
    sort1<<<EB, 256, 0, stream>>>(cnt, blockhist);
    sort2<<<1, 1024, 0, stream>>>(blockhist);
    sort3<<<EB, 256, 0, stream>>>(cnt, blockhist, perm);
    // embed
    P8 Pe;
    for (int i = 0; i < 8; ++i) Pe.p[i] = reg[(i < K) ? cur[i] : 0];
    embed2<CW><<<E_EDGES / 8, 256, 0, stream>>>(x_dftb, W0, b0, Pe);
    // 2 message-passing steps, K chunks each
    for (int step = 0; step < 2; ++step) {
        const float* Ws = Wmp + step * 27648;
        const float* bs = bmp + step * 864;
        for (int h = 0; h < K; ++h) {
            mp_pull<CW><<<E_EDGES / EPB, 256, 0, stream>>>(
                reg[cur[h]], reg[spare], coords, row_start, eidx, src, perm, Ws, bs, G, h);
            int tmp = cur[h]; cur[h] = spare; spare = tmp;
        }
    }
    P8 Pf;
    for (int i = 0; i < 8; ++i) Pf.p[i] = reg[(i < K) ? cur[i] : 0];
    final3<CW><<<1024, 256, 0, stream>>>(Pf, W1, b1, W2, b2, out);
}

extern "C" void kernel_launch(void* const* d_in, const int* in_sizes, int n_in,
                              void* d_out, int out_size, void* d_ws, size_t ws_size,
                              hipStream_t stream) {
    const float* x_dftb = (const float*)d_in[0];
    const float* coords = (const float*)d_in[1];
    const int* dst = (const int*)d_in[2];
    const int* src = (const int*)d_in[3];
    const float* W0 = (const float*)d_in[4];
    const float* b0 = (const float*)d_in[5];
    const float* Wmp = (const float*)d_in[6];
    const float* bmp = (const float*)d_in[7];
    const float* W1 = (const float*)d_in[8];
    const float* b1 = (const float*)d_in[9];
    const float* W2 = (const float*)d_in[10];
    const float* b2 = (const float*)d_in[11];
    float* out = (float*)d_out;
    char* ws = (char*)d_ws;

    size_t slice8 = (size_t)E_EDGES * 9 * 8 * sizeof(float);
    size_t slice4 = (size_t)E_EDGES * 9 * 4 * sizeof(float);
    size_t need8 = REG_OFF + 5 * slice8;   // ~193 MB
    size_t need4 = REG_OFF + 9 * slice4;   // ~174 MB
    if (ws_size >= need8) {
        run_all<8>(x_dftb, coords, dst, src, W0, b0, Wmp, bmp, W1, b1, W2, b2, out, ws, stream);
    } else if (ws_size >= need4) {
        run_all<4>(x_dftb, coords, dst, src, W0, b0, Wmp, bmp, W1, b1, W2, b2, out, ws, stream);
    } else {
        zero_kernel<<<(out_size + 255) / 256, 256, 0, stream>>>(out, (size_t)out_size);
    }
}

// Round 7
// 1266.124 us; speedup vs baseline: 2.4080x; 1.0263x over previous
//
#include <hip/hip_runtime.h>

#define E_EDGES 131072
#define FIN 16
#define FF 32
#define REG_OFF (4u << 20)  // 4 MB reserved: Gaunt + CSR + sort arrays

// ---- combo tables: 11 allowed (l1,l2,l3); blocks l=0:[0,1) l=1:[1,4) l=2:[4,9) ----
constexpr int CIDX[11] = {0, 4, 8, 10, 12, 14, 16, 20, 22, 24, 26};
constexpr int CA0[11] = {0, 0, 0, 1, 1, 1, 1, 4, 4, 4, 4};
constexpr int CDA[11] = {1, 1, 1, 3, 3, 3, 3, 5, 5, 5, 5};
constexpr int CQ0[11] = {0, 1, 4, 0, 1, 1, 4, 0, 1, 4, 4};
constexpr int CC0[11] = {0, 1, 4, 1, 0, 4, 1, 4, 1, 0, 4};
constexpr int CDC[11] = {1, 3, 5, 3, 1, 5, 3, 5, 3, 1, 5};
constexpr int CL2[11] = {0, 1, 2, 0, 1, 1, 2, 0, 1, 2, 2};
constexpr int CZ0[11] = {0, 1, 4, 9, 18, 21, 36, 45, 70, 85, 90};    // unpadded cum, 115
constexpr int CZP[11] = {0, 4, 8, 16, 28, 32, 48, 60, 88, 104, 112}; // pad4 offsets, 140

struct P8 { float* p[8]; };

// ---------------- Gaunt tensor via exact quadrature (matches reference) -------------
__global__ void gaunt_init(float* __restrict__ G) {
    __shared__ double Ys[128][9];
    __shared__ double wq[128];
    const double ct[8] = {
        -0.9602898564975363, -0.7966664774136267, -0.5255324099163290, -0.1834346424956498,
         0.1834346424956498,  0.5255324099163290,  0.7966664774136267,  0.9602898564975363};
    const double wgt[8] = {
        0.1012285362903763, 0.2223810344533745, 0.3137066458778873, 0.3626837833783620,
        0.3626837833783620, 0.3137066458778873, 0.2223810344533745, 0.1012285362903763};
    const double PI = 3.141592653589793238462643383279502884;
    int t = threadIdx.x;
    if (t < 128) {
        int iq = t >> 4, ip = t & 15;
        double c = ct[iq];
        double s = sqrt(1.0 - c * c);
        double phi = (double)ip * (2.0 * PI / 16.0);
        double x = s * cos(phi), y = s * sin(phi), z = c;
        double* Yp = Ys[t];
        Yp[0] = 0.28209479177387814;
        Yp[1] = 0.4886025119029199 * y;
        Yp[2] = 0.4886025119029199 * z;
        Yp[3] = 0.4886025119029199 * x;
        Yp[4] = 1.0925484305920792 * x * y;
        Yp[5] = 1.0925484305920792 * y * z;
        Yp[6] = 0.31539156525252005 * (3.0 * z * z - 1.0);
        Yp[7] = 1.0925484305920792 * x * z;
        Yp[8] = 0.5462742152960396 * (x * x - y * y);
        wq[t] = wgt[iq] * (2.0 * PI / 16.0);
    }
    __syncthreads();
    for (int idx = t; idx < 729; idx += blockDim.x) {
        int a = idx / 81, b = (idx / 9) % 9, cc = idx % 9;
        double sum = 0.0;
        for (int q = 0; q < 128; ++q) sum += wq[q] * Ys[q][a] * Ys[q][b] * Ys[q][cc];
        G[idx] = (float)sum;
    }
}

// ---------------- small utility kernels ---------------------------------------------
__global__ __launch_bounds__(256) void zero_kernel(float* __restrict__ p, size_t n) {
    size_t i = (size_t)blockIdx.x * 256 + threadIdx.x;
    if (i < n) p[i] = 0.f;
}
__global__ __launch_bounds__(256) void fill_int(int* __restrict__ p, int n, int v) {
    int i = blockIdx.x * 256 + threadIdx.x;
    if (i < n) p[i] = v;
}

// ---------------- CSR build ----------------------------------------------------------
__global__ __launch_bounds__(256) void csr_count(const int* __restrict__ dst,
                                                 int* __restrict__ cnt) {
    int e = blockIdx.x * 256 + threadIdx.x;
    atomicAdd(&cnt[dst[e]], 1);  // 131072 spread addresses: low contention
}
__global__ __launch_bounds__(256) void csr_bsum(const int* __restrict__ cnt,
                                                int* __restrict__ bsum) {
    int i = blockIdx.x * 256 + threadIdx.x;
    int v = cnt[i];
#pragma unroll
    for (int off = 32; off; off >>= 1) v += __shfl_down(v, off, 64);
    __shared__ int w4[4];
    if ((threadIdx.x & 63) == 0) w4[threadIdx.x >> 6] = v;
    __syncthreads();
    if (threadIdx.x == 0) bsum[blockIdx.x] = w4[0] + w4[1] + w4[2] + w4[3];
}
// exclusive scan of 512 ints, one wave, shuffle-based
__global__ void scan512_wave(int* __restrict__ b) {
    int lane = threadIdx.x;  // 64 threads
    int run = 0;
    for (int c = 0; c < 8; ++c) {
        int v = b[c * 64 + lane];
        int s = v;
#pragma unroll
        for (int off = 1; off < 64; off <<= 1) {
            int t = __shfl_up(s, off, 64);
            if (lane >= off) s += t;
        }
        b[c * 64 + lane] = run + s - v;
        run += __shfl(s, 63, 64);
    }
}
__global__ __launch_bounds__(256) void csr_row(const int* __restrict__ cnt,
                                               const int* __restrict__ bsum,
                                               int* __restrict__ row_start,
                                               int* __restrict__ cursor) {
    __shared__ int sd[256];
    const int i = blockIdx.x * 256 + threadIdx.x;
    const int my = cnt[i];
    sd[threadIdx.x] = my;
    __syncthreads();
    for (int off = 1; off < 256; off <<= 1) {
        int t = (threadIdx.x >= off) ? sd[threadIdx.x - off] : 0;
        __syncthreads();
        sd[threadIdx.x] += t;
        __syncthreads();
    }
    int rs = bsum[blockIdx.x] + sd[threadIdx.x] - my;
    row_start[i] = rs;
    cursor[i] = rs;
    if (blockIdx.x == 511 && threadIdx.x == 255)
        row_start[E_EDGES] = bsum[511] + sd[255];
}
__global__ __launch_bounds__(256) void csr_scatter(const int* __restrict__ dst,
                                                   int* __restrict__ cursor,
                                                   int* __restrict__ eidx) {
    int e = blockIdx.x * 256 + threadIdx.x;
    int pos = atomicAdd(&cursor[dst[e]], 1);  // spread addresses: fine
    eidx[pos] = e;
}

// ---------------- degree counting-sort (no contended global atomics) ----------------
__global__ __launch_bounds__(256) void sort1(const int* __restrict__ cnt,
                                             int* __restrict__ blockhist) {
    __shared__ int h[32];
    if (threadIdx.x < 32) h[threadIdx.x] = 0;
    __syncthreads();
    int n = blockIdx.x * 256 + threadIdx.x;
    int d = cnt[n]; if (d > 31) d = 31;
    atomicAdd(&h[d], 1);  // LDS atomic, cheap
    __syncthreads();
    if (threadIdx.x < 32) blockhist[threadIdx.x * 512 + blockIdx.x] = h[threadIdx.x];
}
__global__ __launch_bounds__(1024) void sort2(int* __restrict__ blockhist) {
    __shared__ int tot[32];
    int wv = threadIdx.x >> 6, lane = threadIdx.x & 63;  // 16 waves, 2 bins each
#pragma unroll
    for (int bi = 0; bi < 2; ++bi) {
        int bin = wv * 2 + bi;
        int run = 0;
        for (int c = 0; c < 8; ++c) {
            int v = blockhist[bin * 512 + c * 64 + lane];
            int s = v;
#pragma unroll
            for (int off = 1; off < 64; off <<= 1) {
                int t = __shfl_up(s, off, 64);
                if (lane >= off) s += t;
            }
            blockhist[bin * 512 + c * 64 + lane] = run + s - v;
            run += __shfl(s, 63, 64);
        }
        if (lane == 0) tot[bin] = run;
    }
    __syncthreads();
    if (threadIdx.x == 0) {
        int run = 0;
        for (int i = 0; i < 32; ++i) { int t = tot[i]; tot[i] = run; run += t; }
    }
    __syncthreads();
#pragma unroll
    for (int bi = 0; bi < 2; ++bi) {
        int bin = wv * 2 + bi;
        int base = tot[bin];
        for (int c = 0; c < 8; ++c) blockhist[bin * 512 + c * 64 + lane] += base;
    }
}
__global__ __launch_bounds__(256) void sort3(const int* __restrict__ cnt,
                                             const int* __restrict__ blockhist,
                                             int* __restrict__ perm) {
    __shared__ int cur[32];
    if (threadIdx.x < 32) cur[threadIdx.x] = blockhist[threadIdx.x * 512 + blockIdx.x];
    __syncthreads();
    int n = blockIdx.x * 256 + threadIdx.x;
    int d = cnt[n]; if (d > 31) d = 31;
    int pos = atomicAdd(&cur[d], 1);  // LDS atomic, cheap
    perm[pos] = n;
}

// ---------------- embed: (E,9,16)@(16->32) into chunk-major regions ------------------
template <int CW>
__global__ __launch_bounds__(256) void embed2(
    const float* __restrict__ xin, const float* __restrict__ W0,
    const float* __restrict__ b0, P8 P) {
    constexpr int K = 32 / CW;
    int tid = threadIdx.x;
    int e = blockIdx.x * 8 + (tid >> 5);
    int f = tid & 31;
    int h = f / CW, fc = f % CW;
    float* Rh = P.p[0];
#pragma unroll
    for (int i = 1; i < K; ++i) Rh = (h == i) ? P.p[i] : Rh;
    const float* xr = xin + (size_t)e * 144;
#pragma unroll
    for (int c = 0; c < 9; ++c) {
        int l = (c == 0) ? 0 : ((c < 4) ? 1 : 2);
        const float* Wl = W0 + l * FIN * FF;
        float acc = (c == 0) ? b0[f] : 0.f;
#pragma unroll
        for (int q = 0; q < 4; ++q) {
            float4 xv = *(const float4*)&xr[c * 16 + q * 4];
            acc = fmaf(xv.x, Wl[(q * 4 + 0) * 32 + f], acc);
            acc = fmaf(xv.y, Wl[(q * 4 + 1) * 32 + f], acc);
            acc = fmaf(xv.z, Wl[(q * 4 + 2) * 32 + f], acc);
            acc = fmaf(xv.w, Wl[(q * 4 + 3) * 32 + f], acc);
        }
        Rh[((size_t)e * 9 + c) * CW + fc] = acc;
    }
}

// ---------------- per-combo einsum piece (all compile-time indexed) -----------------
template <int K>
__device__ __forceinline__ void comboP(const float* __restrict__ zrow,
                                       const float (&coef)[11], const float (&xa)[9],
                                       float (&acc)[9]) {
    constexpr int A0 = CA0[K], DA = CDA[K], C0 = CC0[K], DC = CDC[K];
    constexpr int SZ = DA * DC, N4 = (SZ + 3) / 4, ZP = CZP[K];
    float zz[N4 * 4];
    const float4* zp = (const float4*)(zrow + ZP);
#pragma unroll
    for (int j = 0; j < N4; ++j) {
        float4 v = zp[j];
        zz[4 * j + 0] = v.x; zz[4 * j + 1] = v.y; zz[4 * j + 2] = v.z; zz[4 * j + 3] = v.w;
    }
    float m[DC] = {};
#pragma unroll
    for (int a = 0; a < DA; ++a)
#pragma unroll
        for (int c = 0; c < DC; ++c) m[c] = fmaf(xa[A0 + a], zz[a * DC + c], m[c]);
#pragma unroll
    for (int c = 0; c < DC; ++c) acc[C0 + c] = fmaf(coef[K], m[c], acc[C0 + c]);
}

// ---------------- message pass, CSR pull, chunk h, persistent blocks ----------------
template <int CW>
__global__ __launch_bounds__(256) void mp_pull2(
    const float* __restrict__ Xold, float* __restrict__ Xnew,
    const float* __restrict__ coords,
    const int* __restrict__ row_start, const int* __restrict__ eidx,
    const int* __restrict__ src, const int* __restrict__ perm,
    const float* __restrict__ Wm, const float* __restrict__ bm,
    const float* __restrict__ Gglob, int h) {
    constexpr int EPB = 256 / CW;
    constexpr int NB_TOT = E_EDGES / EPB;
    __shared__ float gG[729];
    __shared__ int tab[115];
    __shared__ float W_s[11 * CW * 36];
    __shared__ float z_s[EPB * 140];
    const int tid = threadIdx.x;
    for (int i = tid; i < 729; i += 256) gG[i] = Gglob[i];
    for (int t = tid; t < 115; t += 256) {
        int k = 0;
#pragma unroll
        for (int kk = 1; kk < 11; ++kk) if (t >= CZ0[kk]) k = kk;
        int loc = t - CZ0[k];
        int dc = CDC[k];
        int a = loc / dc, c = loc - a * dc;
        int base = (CA0[k] + a) * 81 + CQ0[k] * 9 + (CC0[k] + c);
        tab[t] = ((CZP[k] + loc) << 12) | (CL2[k] << 10) | base;
    }
    for (int i = tid; i < 11 * CW * 32; i += 256) {
        int k = i / (CW * 32);
        int r2 = i - k * (CW * 32);
        int b = r2 / CW, fc2 = r2 - b * CW;
        W_s[(k * CW + fc2) * 36 + b] = Wm[CIDX[k] * 1024 + b * 32 + h * CW + fc2];
    }
    __syncthreads();

    const int g = tid / CW, fc = tid % CW;
    float* zrow = &z_s[g * 140];
    float bmr[11];
#pragma unroll
    for (int k = 0; k < 11; ++k) bmr[k] = bm[CIDX[k] * 32 + h * CW + fc];

    for (int nb = blockIdx.x; nb < NB_TOT; nb += gridDim.x) {
        const int d = perm[nb * EPB + g];
        const int r0 = row_start[d], r1 = row_start[d + 1];
        float acc[9];
#pragma unroll
        for (int a = 0; a < 9; ++a) acc[a] = Xold[((size_t)d * 9 + a) * CW + fc];
        const float ddx = coords[3 * d], ddy = coords[3 * d + 1], ddz = coords[3 * d + 2];

        // 1-deep software pipeline over the row's edges
        int ps = 0; float pcx = 0.f, pcy = 0.f, pcz = 0.f;
        float pxa[9];
        if (r0 < r1) {
            int pe = eidx[r0]; ps = src[pe];
            pcx = coords[3 * ps]; pcy = coords[3 * ps + 1]; pcz = coords[3 * ps + 2];
#pragma unroll
            for (int a = 0; a < 9; ++a) pxa[a] = Xold[((size_t)ps * 9 + a) * CW + fc];
        }
        for (int p = r0; p < r1; ++p) {
            const float rx = ddx - pcx, ry = ddy - pcy, rz = ddz - pcz;
            float xa[9];
#pragma unroll
            for (int a = 0; a < 9; ++a) xa[a] = pxa[a];
            if (p + 1 < r1) {  // prefetch next edge under this edge's compute
                int pe = eidx[p + 1]; ps = src[pe];
                pcx = coords[3 * ps]; pcy = coords[3 * ps + 1]; pcz = coords[3 * ps + 2];
#pragma unroll
                for (int a = 0; a < 9; ++a) pxa[a] = Xold[((size_t)ps * 9 + a) * CW + fc];
            }
            float r = sqrtf(rx * rx + ry * ry + rz * rz + 1e-8f);
            float inv = 1.f / r;
            float ux = rx * inv, uy = ry * inv, uz = rz * inv;
            float y9[9];
            y9[0] = 0.28209479177387814f;
            y9[1] = 0.4886025119029199f * uy; y9[2] = 0.4886025119029199f * uz;
            y9[3] = 0.4886025119029199f * ux;
            y9[4] = 1.0925484305920792f * ux * uy; y9[5] = 1.0925484305920792f * uy * uz;
            y9[6] = 0.31539156525252005f * (3.f * uz * uz - 1.f);
            y9[7] = 1.0925484305920792f * ux * uz;
            y9[8] = 0.5462742152960396f * (ux * ux - uy * uy);
            // radial basis: lane owns centers b = fc + j*CW, broadcast via shuffle
            float radj[32 / CW];
#pragma unroll
            for (int j = 0; j < 32 / CW; ++j) {
                int b = fc + j * CW;
                float cb = (float)((double)b * (4.0 / 31.0));
                float dr = r - cb;
                radj[j] = expf(-dr * dr);
            }
            float radv[32];
#pragma unroll
            for (int b = 0; b < 32; ++b) radv[b] = __shfl(radj[b / CW], b % CW, CW);
            // z[t] = sum_b Y[Q0+b] * G[base + 9b], distributed over group, LDS-shared
            for (int t = fc; t < 115; t += CW) {
                int u = tab[t];
                int base = u & 0x3FF;
                int l2u = (u >> 10) & 3;
                float zv;
                if (l2u == 0) {
                    zv = y9[0] * gG[base];
                } else if (l2u == 1) {
                    zv = y9[1] * gG[base];
                    zv = fmaf(y9[2], gG[base + 9], zv);
                    zv = fmaf(y9[3], gG[base + 18], zv);
                } else {
                    zv = y9[4] * gG[base];
                    zv = fmaf(y9[5], gG[base + 9], zv);
                    zv = fmaf(y9[6], gG[base + 18], zv);
                    zv = fmaf(y9[7], gG[base + 27], zv);
                    zv = fmaf(y9[8], gG[base + 36], zv);
                }
                zrow[u >> 12] = zv;
            }
            asm volatile("s_waitcnt lgkmcnt(0)" ::: "memory");
            // coef[k] = bm + rad @ W  (W from LDS, b128, conflict-free via 36-pad)
            float coef[11];
#pragma unroll
            for (int k = 0; k < 11; ++k) {
                float cc = bmr[k];
                const float4* wp = (const float4*)&W_s[(k * CW + fc) * 36];
#pragma unroll
                for (int b4 = 0; b4 < 8; ++b4) {
                    float4 w = wp[b4];
                    cc = fmaf(radv[b4 * 4 + 0], w.x, cc);
                    cc = fmaf(radv[b4 * 4 + 1], w.y, cc);
                    cc = fmaf(radv[b4 * 4 + 2], w.z, cc);
                    cc = fmaf(radv[b4 * 4 + 3], w.w, cc);
                }
                coef[k] = cc;
            }
            comboP<0>(zrow, coef, xa, acc);
            comboP<1>(zrow, coef, xa, acc);
            comboP<2>(zrow, coef, xa, acc);
            comboP<3>(zrow, coef, xa, acc);
            comboP<4>(zrow, coef, xa, acc);
            comboP<5>(zrow, coef, xa, acc);
            comboP<6>(zrow, coef, xa, acc);
            comboP<7>(zrow, coef, xa, acc);
            comboP<8>(zrow, coef, xa, acc);
            comboP<9>(zrow, coef, xa, acc);
            comboP<10>(zrow, coef, xa, acc);
        }
#pragma unroll
        for (int a = 0; a < 9; ++a) Xnew[((size_t)d * 9 + a) * CW + fc] = acc[a];
    }
}

// ---------------- final: dense(32->32)+gate+dense(32->1), barrier-free --------------
template <int CW>
__global__ __launch_bounds__(256) void final5(
    P8 P, const float* __restrict__ W1, const float* __restrict__ b1,
    const float* __restrict__ W2, const float* __restrict__ b2,
    float* __restrict__ out) {
    constexpr int K = 32 / CW;
    __shared__ float Xw[4][2][9][36];  // per-wave slots: no __syncthreads needed
    const int w = threadIdx.x >> 6;
    const int lane = threadIdx.x & 63;
    const int hh = lane >> 5;
    const int f = lane & 31;
    const int fc = f % CW;
    const float* Rh = P.p[0];
#pragma unroll
    for (int i = 1; i < K; ++i) Rh = ((f / CW) == i) ? P.p[i] : Rh;
    float w1r[3][32];
#pragma unroll
    for (int l = 0; l < 3; ++l)
#pragma unroll
        for (int q = 0; q < 32; ++q) w1r[l][q] = W1[(l * 32 + q) * 32 + f];
    float w2r[3];
#pragma unroll
    for (int l = 0; l < 3; ++l) w2r[l] = W2[l * 32 + f];
    const float b1f = b1[f], b20 = b2[0];
    const int wv = (blockIdx.x * 256 + threadIdx.x) >> 6;
    const int nw = (gridDim.x * 256) >> 6;
    for (int ep = wv; ep < E_EDGES / 2; ep += nw) {
        const int e = ep * 2 + hh;
        // wave-local transpose: own f-column -> LDS rows (writes 2-way banked = free)
#pragma unroll
        for (int c = 0; c < 9; ++c)
            Xw[w][hh][c][f] = Rh[((size_t)e * 9 + c) * CW + fc];
        asm volatile("s_waitcnt lgkmcnt(0)" ::: "memory");  // intra-wave, no barrier
        float t[9];
#pragma unroll
        for (int c = 0; c < 9; ++c) {
            const int l = (c == 0) ? 0 : ((c < 4) ? 1 : 2);
            float acc = (c == 0) ? b1f : 0.f;
            const float4* xp = (const float4*)&Xw[w][hh][c][0];
#pragma unroll
            for (int q = 0; q < 8; ++q) {
                float4 xv = xp[q];
                acc = fmaf(xv.x, w1r[l][q * 4 + 0], acc);
                acc = fmaf(xv.y, w1r[l][q * 4 + 1], acc);
                acc = fmaf(xv.z, w1r[l][q * 4 + 2], acc);
                acc = fmaf(xv.w, w1r[l][q * 4 + 3], acc);
            }
            t[c] = acc;
        }
        const float gate = (t[0] > 0.f) ? 1.f : 0.f;
#pragma unroll
        for (int c = 0; c < 9; ++c) {
            const int l = (c == 0) ? 0 : ((c < 4) ? 1 : 2);
            float v = t[c] * gate * w2r[l];
#pragma unroll
            for (int off = 16; off; off >>= 1) v += __shfl_xor(v, off, 32);
            if (f == 0) out[(size_t)e * 9 + c] = v + ((c == 0) ? b20 : 0.f);
        }
    }
}

// ---------------- driver -------------------------------------------------------------
template <int CW>
static void run_all(const float* x_dftb, const float* coords, const int* dst,
                    const int* src, const float* W0, const float* b0,
                    const float* Wmp, const float* bmp, const float* W1,
                    const float* b1, const float* W2, const float* b2,
                    float* out, char* ws, hipStream_t stream) {
    constexpr int K = 32 / CW;
    size_t sliceB = (size_t)E_EDGES * 9 * CW * sizeof(float);
    float* G = (float*)ws;
    int* row_start = (int*)(ws + 4096);
    int* eidx = (int*)(ws + 4096 + 1 * 640 * 1024);
    int* cnt = (int*)(ws + 4096 + 2 * 640 * 1024);
    int* cursor = (int*)(ws + 4096 + 3 * 640 * 1024);
    int* perm = (int*)(ws + 4096 + 4 * 640 * 1024);
    int* bsum = (int*)(ws + 4096 + 5 * 640 * 1024);                   // 512 ints
    int* blockhist = (int*)(ws + 4096 + 5 * 640 * 1024 + 64 * 1024);  // 32*512 ints

    float* reg[K + 1];
    for (int i = 0; i <= K; ++i) reg[i] = (float*)(ws + REG_OFF + (size_t)i * sliceB);
    int cur[K];
    for (int i = 0; i < K; ++i) cur[i] = i;
    int spare = K;

    const int EB = E_EDGES / 256;  // 512
    gaunt_init<<<1, 256, 0, stream>>>(G);
    fill_int<<<EB, 256, 0, stream>>>(cnt, E_EDGES, 0);
    csr_count<<<EB, 256, 0, stream>>>(dst, cnt);
    csr_bsum<<<EB, 256, 0, stream>>>(cnt, bsum);
    scan512_wave<<<1, 64, 0, stream>>>(bsum);
    csr_row<<<EB, 256, 0, stream>>>(cnt, bsum, row_start, cursor);
    csr_scatter<<<EB, 256, 0, stream>>>(dst, cursor, eidx);
    sort1<<<EB, 256, 0, stream>>>(cnt, blockhist);
    sort2<<<1, 1024, 0, stream>>>(blockhist);
    sort3<<<EB, 256, 0, stream>>>(cnt, blockhist, perm);

    P8 Pe;
    for (int i = 0; i < 8; ++i) Pe.p[i] = reg[(i < K) ? cur[i] : 0];
    embed2<CW><<<E_EDGES / 8, 256, 0, stream>>>(x_dftb, W0, b0, Pe);

    const int mp_grid = (CW == 8) ? 1024 : 768;  // 4 (resp. 3) blocks/CU by LDS
    for (int step = 0; step < 2; ++step) {
        const float* Ws = Wmp + step * 27648;
        const float* bs = bmp + step * 864;
        for (int h = 0; h < K; ++h) {
            mp_pull2<CW><<<mp_grid, 256, 0, stream>>>(
                reg[cur[h]], reg[spare], coords, row_start, eidx, src, perm, Ws, bs, G, h);
            int tmp = cur[h]; cur[h] = spare; spare = tmp;
        }
    }
    P8 Pf;
    for (int i = 0; i < 8; ++i) Pf.p[i] = reg[(i < K) ? cur[i] : 0];
    final5<CW><<<2048, 256, 0, stream>>>(Pf, W1, b1, W2, b2, out);
}

extern "C" void kernel_launch(void* const* d_in, const int* in_sizes, int n_in,
                              void* d_out, int out_size, void* d_ws, size_t ws_size,
                              hipStream_t stream) {
    const float* x_dftb = (const float*)d_in[0];
    const float* coords = (const float*)d_in[1];
    const int* dst = (const int*)d_in[2];
    const int* src = (const int*)d_in[3];
    const float* W0 = (const float*)d_in[4];
    const float* b0 = (const float*)d_in[5];
    const float* Wmp = (const float*)d_in[6];
    const float* bmp = (const float*)d_in[7];
    const float* W1 = (const float*)d_in[8];
    const float* b1 = (const float*)d_in[9];
    const float* W2 = (const float*)d_in[10];
    const float* b2 = (const float*)d_in[11];
    float* out = (float*)d_out;
    char* ws = (char*)d_ws;

    size_t slice8 = (size_t)E_EDGES * 9 * 8 * sizeof(float);
    size_t slice4 = (size_t)E_EDGES * 9 * 4 * sizeof(float);
    size_t need8 = REG_OFF + 5 * slice8;   // ~184 MiB
    size_t need4 = REG_OFF + 9 * slice4;   // ~166 MiB
    if (ws_size >= need8) {
        run_all<8>(x_dftb, coords, dst, src, W0, b0, Wmp, bmp, W1, b1, W2, b2, out, ws, stream);
    } else if (ws_size >= need4) {
        run_all<4>(x_dftb, coords, dst, src, W0, b0, Wmp, bmp, W1, b1, W2, b2, out, ws, stream);
    } else {
        zero_kernel<<<(out_size + 255) / 256, 256, 0, stream>>>(out, (size_t)out_size);
    }
}

// Round 8
// 1143.898 us; speedup vs baseline: 2.6653x; 1.1069x over previous
//
#include <hip/hip_runtime.h>

#define E_EDGES 131072
#define FIN 16
#define FF 32
#define REG_OFF (4u << 20)  // 4 MB reserved: Gaunt + CSR + sort + coef-table arrays

// ---- combo tables: 11 allowed (l1,l2,l3); blocks l=0:[0,1) l=1:[1,4) l=2:[4,9) ----
constexpr int CIDX[11] = {0, 4, 8, 10, 12, 14, 16, 20, 22, 24, 26};
constexpr int CA0[11] = {0, 0, 0, 1, 1, 1, 1, 4, 4, 4, 4};
constexpr int CDA[11] = {1, 1, 1, 3, 3, 3, 3, 5, 5, 5, 5};
constexpr int CQ0[11] = {0, 1, 4, 0, 1, 1, 4, 0, 1, 4, 4};
constexpr int CC0[11] = {0, 1, 4, 1, 0, 4, 1, 4, 1, 0, 4};
constexpr int CDC[11] = {1, 3, 5, 3, 1, 5, 3, 5, 3, 1, 5};
constexpr int CL2[11] = {0, 1, 2, 0, 1, 1, 2, 0, 1, 2, 2};
constexpr int CZ0[11] = {0, 1, 4, 9, 18, 21, 36, 45, 70, 85, 90};    // unpadded cum, 115
constexpr int CZP[11] = {0, 4, 8, 16, 28, 32, 48, 60, 88, 104, 112}; // pad4 offsets, 140

#define TBL_N 768
#define TBL_RMAX 12.0
#define TBL_INVH ((float)(767.0 / 12.0))

struct P8 { float* p[8]; };

// ---------------- Gaunt tensor via exact quadrature (matches reference) -------------
__global__ void gaunt_init(float* __restrict__ G) {
    __shared__ double Ys[128][9];
    __shared__ double wq[128];
    const double ct[8] = {
        -0.9602898564975363, -0.7966664774136267, -0.5255324099163290, -0.1834346424956498,
         0.1834346424956498,  0.5255324099163290,  0.7966664774136267,  0.9602898564975363};
    const double wgt[8] = {
        0.1012285362903763, 0.2223810344533745, 0.3137066458778873, 0.3626837833783620,
        0.3626837833783620, 0.3137066458778873, 0.2223810344533745, 0.1012285362903763};
    const double PI = 3.141592653589793238462643383279502884;
    int t = threadIdx.x;
    if (t < 128) {
        int iq = t >> 4, ip = t & 15;
        double c = ct[iq];
        double s = sqrt(1.0 - c * c);
        double phi = (double)ip * (2.0 * PI / 16.0);
        double x = s * cos(phi), y = s * sin(phi), z = c;
        double* Yp = Ys[t];
        Yp[0] = 0.28209479177387814;
        Yp[1] = 0.4886025119029199 * y;
        Yp[2] = 0.4886025119029199 * z;
        Yp[3] = 0.4886025119029199 * x;
        Yp[4] = 1.0925484305920792 * x * y;
        Yp[5] = 1.0925484305920792 * y * z;
        Yp[6] = 0.31539156525252005 * (3.0 * z * z - 1.0);
        Yp[7] = 1.0925484305920792 * x * z;
        Yp[8] = 0.5462742152960396 * (x * x - y * y);
        wq[t] = wgt[iq] * (2.0 * PI / 16.0);
    }
    __syncthreads();
    for (int idx = t; idx < 729; idx += blockDim.x) {
        int a = idx / 81, b = (idx / 9) % 9, cc = idx % 9;
        double sum = 0.0;
        for (int q = 0; q < 128; ++q) sum += wq[q] * Ys[q][a] * Ys[q][b] * Ys[q][cc];
        G[idx] = (float)sum;
    }
}

// ---------------- small utility kernels ---------------------------------------------
__global__ __launch_bounds__(256) void zero_kernel(float* __restrict__ p, size_t n) {
    size_t i = (size_t)blockIdx.x * 256 + threadIdx.x;
    if (i < n) p[i] = 0.f;
}
__global__ __launch_bounds__(256) void fill_int(int* __restrict__ p, int n, int v) {
    int i = blockIdx.x * 256 + threadIdx.x;
    if (i < n) p[i] = v;
}

// ---------------- CSR build ----------------------------------------------------------
__global__ __launch_bounds__(256) void csr_count(const int* __restrict__ dst,
                                                 int* __restrict__ cnt) {
    int e = blockIdx.x * 256 + threadIdx.x;
    atomicAdd(&cnt[dst[e]], 1);  // 131072 spread addresses: low contention
}
__global__ __launch_bounds__(256) void csr_bsum(const int* __restrict__ cnt,
                                                int* __restrict__ bsum) {
    int i = blockIdx.x * 256 + threadIdx.x;
    int v = cnt[i];
#pragma unroll
    for (int off = 32; off; off >>= 1) v += __shfl_down(v, off, 64);
    __shared__ int w4[4];
    if ((threadIdx.x & 63) == 0) w4[threadIdx.x >> 6] = v;
    __syncthreads();
    if (threadIdx.x == 0) bsum[blockIdx.x] = w4[0] + w4[1] + w4[2] + w4[3];
}
__global__ void scan512_wave(int* __restrict__ b) {
    int lane = threadIdx.x;  // 64 threads
    int run = 0;
    for (int c = 0; c < 8; ++c) {
        int v = b[c * 64 + lane];
        int s = v;
#pragma unroll
        for (int off = 1; off < 64; off <<= 1) {
            int t = __shfl_up(s, off, 64);
            if (lane >= off) s += t;
        }
        b[c * 64 + lane] = run + s - v;
        run += __shfl(s, 63, 64);
    }
}
__global__ __launch_bounds__(256) void csr_row(const int* __restrict__ cnt,
                                               const int* __restrict__ bsum,
                                               int* __restrict__ row_start,
                                               int* __restrict__ cursor) {
    __shared__ int sd[256];
    const int i = blockIdx.x * 256 + threadIdx.x;
    const int my = cnt[i];
    sd[threadIdx.x] = my;
    __syncthreads();
    for (int off = 1; off < 256; off <<= 1) {
        int t = (threadIdx.x >= off) ? sd[threadIdx.x - off] : 0;
        __syncthreads();
        sd[threadIdx.x] += t;
        __syncthreads();
    }
    int rs = bsum[blockIdx.x] + sd[threadIdx.x] - my;
    row_start[i] = rs;
    cursor[i] = rs;
    if (blockIdx.x == 511 && threadIdx.x == 255)
        row_start[E_EDGES] = bsum[511] + sd[255];
}
__global__ __launch_bounds__(256) void csr_scatter(const int* __restrict__ dst,
                                                   int* __restrict__ cursor,
                                                   int* __restrict__ eidx) {
    int e = blockIdx.x * 256 + threadIdx.x;
    int pos = atomicAdd(&cursor[dst[e]], 1);  // spread addresses: fine
    eidx[pos] = e;
}

// ---------------- degree counting-sort (no contended global atomics) ----------------
__global__ __launch_bounds__(256) void sort1(const int* __restrict__ cnt,
                                             int* __restrict__ blockhist) {
    __shared__ int h[32];
    if (threadIdx.x < 32) h[threadIdx.x] = 0;
    __syncthreads();
    int n = blockIdx.x * 256 + threadIdx.x;
    int d = cnt[n]; if (d > 31) d = 31;
    atomicAdd(&h[d], 1);  // LDS atomic, cheap
    __syncthreads();
    if (threadIdx.x < 32) blockhist[threadIdx.x * 512 + blockIdx.x] = h[threadIdx.x];
}
__global__ __launch_bounds__(1024) void sort2(int* __restrict__ blockhist) {
    __shared__ int tot[32];
    int wv = threadIdx.x >> 6, lane = threadIdx.x & 63;  // 16 waves, 2 bins each
#pragma unroll
    for (int bi = 0; bi < 2; ++bi) {
        int bin = wv * 2 + bi;
        int run = 0;
        for (int c = 0; c < 8; ++c) {
            int v = blockhist[bin * 512 + c * 64 + lane];
            int s = v;
#pragma unroll
            for (int off = 1; off < 64; off <<= 1) {
                int t = __shfl_up(s, off, 64);
                if (lane >= off) s += t;
            }
            blockhist[bin * 512 + c * 64 + lane] = run + s - v;
            run += __shfl(s, 63, 64);
        }
        if (lane == 0) tot[bin] = run;
    }
    __syncthreads();
    if (threadIdx.x == 0) {
        int run = 0;
        for (int i = 0; i < 32; ++i) { int t = tot[i]; tot[i] = run; run += t; }
    }
    __syncthreads();
#pragma unroll
    for (int bi = 0; bi < 2; ++bi) {
        int bin = wv * 2 + bi;
        int base = tot[bin];
        for (int c = 0; c < 8; ++c) blockhist[bin * 512 + c * 64 + lane] += base;
    }
}
__global__ __launch_bounds__(256) void sort3(const int* __restrict__ cnt,
                                             const int* __restrict__ blockhist,
                                             int* __restrict__ perm) {
    __shared__ int cur[32];
    if (threadIdx.x < 32) cur[threadIdx.x] = blockhist[threadIdx.x * 512 + blockIdx.x];
    __syncthreads();
    int n = blockIdx.x * 256 + threadIdx.x;
    int d = cnt[n]; if (d > 31) d = 31;
    int pos = atomicAdd(&cur[d], 1);  // LDS atomic, cheap
    perm[pos] = n;
}

// ---------------- coef lookup table: T[u][k][f] = bm + rad(u*h) @ W -----------------
__global__ __launch_bounds__(256) void build_tbl(const float* __restrict__ Wm,
                                                 const float* __restrict__ bm,
                                                 float* __restrict__ tbl) {
    __shared__ float rad[32];
    const int u = blockIdx.x;
    const int tid = threadIdx.x;
    if (tid < 32) {
        double r = (double)u * (TBL_RMAX / (double)(TBL_N - 1));
        double c = (double)tid * (4.0 / 31.0);
        double d = r - c;
        rad[tid] = (float)exp(-d * d);
    }
    __syncthreads();
    for (int i = tid; i < 352; i += 256) {
        int k = i >> 5, f = i & 31;
        float acc = bm[CIDX[k] * 32 + f];
        const float* W = Wm + CIDX[k] * 1024 + f;
#pragma unroll
        for (int b = 0; b < 32; ++b) acc = fmaf(rad[b], W[b * 32], acc);
        tbl[(size_t)u * 352 + i] = acc;
    }
}

// ---------------- embed: (E,9,16)@(16->32) into chunk-major regions ------------------
template <int CW>
__global__ __launch_bounds__(256) void embed2(
    const float* __restrict__ xin, const float* __restrict__ W0,
    const float* __restrict__ b0, P8 P) {
    constexpr int K = 32 / CW;
    int tid = threadIdx.x;
    int e = blockIdx.x * 8 + (tid >> 5);
    int f = tid & 31;
    int h = f / CW, fc = f % CW;
    float* Rh = P.p[0];
#pragma unroll
    for (int i = 1; i < K; ++i) Rh = (h == i) ? P.p[i] : Rh;
    const float* xr = xin + (size_t)e * 144;
#pragma unroll
    for (int c = 0; c < 9; ++c) {
        int l = (c == 0) ? 0 : ((c < 4) ? 1 : 2);
        const float* Wl = W0 + l * FIN * FF;
        float acc = (c == 0) ? b0[f] : 0.f;
#pragma unroll
        for (int q = 0; q < 4; ++q) {
            float4 xv = *(const float4*)&xr[c * 16 + q * 4];
            acc = fmaf(xv.x, Wl[(q * 4 + 0) * 32 + f], acc);
            acc = fmaf(xv.y, Wl[(q * 4 + 1) * 32 + f], acc);
            acc = fmaf(xv.z, Wl[(q * 4 + 2) * 32 + f], acc);
            acc = fmaf(xv.w, Wl[(q * 4 + 3) * 32 + f], acc);
        }
        Rh[((size_t)e * 9 + c) * CW + fc] = acc;
    }
}

// ---------------- per-combo einsum piece (all compile-time indexed) -----------------
template <int K>
__device__ __forceinline__ void comboP(const float* __restrict__ zrow,
                                       const float (&coef)[11], const float (&xa)[9],
                                       float (&acc)[9]) {
    constexpr int A0 = CA0[K], DA = CDA[K], C0 = CC0[K], DC = CDC[K];
    constexpr int SZ = DA * DC, N4 = (SZ + 3) / 4, ZP = CZP[K];
    float zz[N4 * 4];
    const float4* zp = (const float4*)(zrow + ZP);
#pragma unroll
    for (int j = 0; j < N4; ++j) {
        float4 v = zp[j];
        zz[4 * j + 0] = v.x; zz[4 * j + 1] = v.y; zz[4 * j + 2] = v.z; zz[4 * j + 3] = v.w;
    }
    float m[DC] = {};
#pragma unroll
    for (int a = 0; a < DA; ++a)
#pragma unroll
        for (int c = 0; c < DC; ++c) m[c] = fmaf(xa[A0 + a], zz[a * DC + c], m[c]);
#pragma unroll
    for (int c = 0; c < DC; ++c) acc[C0 + c] = fmaf(coef[K], m[c], acc[C0 + c]);
}

// ---------------- message pass, CSR pull, chunk h, table coef -----------------------
template <int CW>
__global__ __launch_bounds__(256) void mp_pull3(
    const float* __restrict__ Xold, float* __restrict__ Xnew,
    const float* __restrict__ coords,
    const int* __restrict__ row_start, const int* __restrict__ eidx,
    const int* __restrict__ src, const int* __restrict__ perm,
    const float* __restrict__ tbl, const float* __restrict__ Gglob, int h) {
    constexpr int EPB = 256 / CW;
    constexpr int NB_TOT = E_EDGES / EPB;
    __shared__ float gG[729];
    __shared__ int tab[115];
    __shared__ float z_s[EPB * 140];
    const int tid = threadIdx.x;
    for (int i = tid; i < 729; i += 256) gG[i] = Gglob[i];
    for (int t = tid; t < 115; t += 256) {
        int k = 0;
#pragma unroll
        for (int kk = 1; kk < 11; ++kk) if (t >= CZ0[kk]) k = kk;
        int loc = t - CZ0[k];
        int dc = CDC[k];
        int a = loc / dc, c = loc - a * dc;
        int base = (CA0[k] + a) * 81 + CQ0[k] * 9 + (CC0[k] + c);
        tab[t] = ((CZP[k] + loc) << 12) | (CL2[k] << 10) | base;
    }
    __syncthreads();

    const int g = tid / CW, fc = tid % CW;
    const int f = h * CW + fc;
    float* zrow = &z_s[g * 140];

    for (int nb = blockIdx.x; nb < NB_TOT; nb += gridDim.x) {
        const int d = perm[nb * EPB + g];
        const int r0 = row_start[d], r1 = row_start[d + 1];
        float acc[9];
#pragma unroll
        for (int a = 0; a < 9; ++a) acc[a] = Xold[((size_t)d * 9 + a) * CW + fc];
        const float ddx = coords[3 * d], ddy = coords[3 * d + 1], ddz = coords[3 * d + 2];

        // 1-deep software pipeline over the row's edges
        int ps = 0; float pcx = 0.f, pcy = 0.f, pcz = 0.f;
        float pxa[9];
        if (r0 < r1) {
            int pe = eidx[r0]; ps = src[pe];
            pcx = coords[3 * ps]; pcy = coords[3 * ps + 1]; pcz = coords[3 * ps + 2];
#pragma unroll
            for (int a = 0; a < 9; ++a) pxa[a] = Xold[((size_t)ps * 9 + a) * CW + fc];
        }
        for (int p = r0; p < r1; ++p) {
            const float rx = ddx - pcx, ry = ddy - pcy, rz = ddz - pcz;
            float xa[9];
#pragma unroll
            for (int a = 0; a < 9; ++a) xa[a] = pxa[a];
            if (p + 1 < r1) {  // prefetch next edge under this edge's compute
                int pe = eidx[p + 1]; ps = src[pe];
                pcx = coords[3 * ps]; pcy = coords[3 * ps + 1]; pcz = coords[3 * ps + 2];
#pragma unroll
                for (int a = 0; a < 9; ++a) pxa[a] = Xold[((size_t)ps * 9 + a) * CW + fc];
            }
            float r = sqrtf(rx * rx + ry * ry + rz * rz + 1e-8f);
            float inv = 1.f / r;
            float ux = rx * inv, uy = ry * inv, uz = rz * inv;
            float y9[9];
            y9[0] = 0.28209479177387814f;
            y9[1] = 0.4886025119029199f * uy; y9[2] = 0.4886025119029199f * uz;
            y9[3] = 0.4886025119029199f * ux;
            y9[4] = 1.0925484305920792f * ux * uy; y9[5] = 1.0925484305920792f * uy * uz;
            y9[6] = 0.31539156525252005f * (3.f * uz * uz - 1.f);
            y9[7] = 1.0925484305920792f * ux * uz;
            y9[8] = 0.5462742152960396f * (ux * ux - uy * uy);
            // coef via cubic Lagrange interp of T[u][k][f]  (replaces rad@W GEMM)
            float rt = r * TBL_INVH;
            int u = (int)rt;
            u = (u < 1) ? 1 : ((u > TBL_N - 3) ? (TBL_N - 3) : u);
            float w = rt - (float)u;
            float wp1 = w + 1.f, wm1 = w - 1.f, wm2 = w - 2.f;
            float lm = -w * wm1 * wm2 * (1.f / 6.f);
            float l0 = wp1 * wm1 * wm2 * 0.5f;
            float l1 = -wp1 * w * wm2 * 0.5f;
            float l2 = wp1 * w * wm1 * (1.f / 6.f);
            const float* tb = tbl + (size_t)(u - 1) * 352 + f;
            float coef[11];
#pragma unroll
            for (int k = 0; k < 11; ++k) {
                const float* tk = tb + k * 32;
                float cc = lm * tk[0];
                cc = fmaf(l0, tk[352], cc);
                cc = fmaf(l1, tk[704], cc);
                cc = fmaf(l2, tk[1056], cc);
                coef[k] = cc;
            }
            // z[t] = sum_b Y[Q0+b] * G[base + 9b], distributed over group, LDS-shared
            for (int t = fc; t < 115; t += CW) {
                int u2 = tab[t];
                int base = u2 & 0x3FF;
                int l2u = (u2 >> 10) & 3;
                float zv;
                if (l2u == 0) {
                    zv = y9[0] * gG[base];
                } else if (l2u == 1) {
                    zv = y9[1] * gG[base];
                    zv = fmaf(y9[2], gG[base + 9], zv);
                    zv = fmaf(y9[3], gG[base + 18], zv);
                } else {
                    zv = y9[4] * gG[base];
                    zv = fmaf(y9[5], gG[base + 9], zv);
                    zv = fmaf(y9[6], gG[base + 18], zv);
                    zv = fmaf(y9[7], gG[base + 27], zv);
                    zv = fmaf(y9[8], gG[base + 36], zv);
                }
                zrow[u2 >> 12] = zv;
            }
            asm volatile("s_waitcnt lgkmcnt(0)" ::: "memory");
            comboP<0>(zrow, coef, xa, acc);
            comboP<1>(zrow, coef, xa, acc);
            comboP<2>(zrow, coef, xa, acc);
            comboP<3>(zrow, coef, xa, acc);
            comboP<4>(zrow, coef, xa, acc);
            comboP<5>(zrow, coef, xa, acc);
            comboP<6>(zrow, coef, xa, acc);
            comboP<7>(zrow, coef, xa, acc);
            comboP<8>(zrow, coef, xa, acc);
            comboP<9>(zrow, coef, xa, acc);
            comboP<10>(zrow, coef, xa, acc);
        }
#pragma unroll
        for (int a = 0; a < 9; ++a) Xnew[((size_t)d * 9 + a) * CW + fc] = acc[a];
    }
}

// ---------------- DPP 32-lane reduction (pure VALU, no LDS pipe) --------------------
template <int CTRL, int RMASK>
__device__ __forceinline__ float dpp_add(float v) {
    int t = __builtin_amdgcn_update_dpp(0, __builtin_bit_cast(int, v),
                                        CTRL, RMASK, 0xF, true);
    return v + __builtin_bit_cast(float, t);
}
__device__ __forceinline__ float red32(float v) {
    v = dpp_add<0x111, 0xF>(v);  // row_shr:1
    v = dpp_add<0x112, 0xF>(v);  // row_shr:2
    v = dpp_add<0x114, 0xF>(v);  // row_shr:4
    v = dpp_add<0x118, 0xF>(v);  // row_shr:8
    v = dpp_add<0x142, 0xA>(v);  // row_bcast:15 into rows 1,3
    return v;                    // lanes 31 and 63 hold their half's sum
}

// ---------------- final: dense(32->32)+gate+dense(32->1), SGPR x + DPP --------------
template <int CW>
__global__ __launch_bounds__(256) void final6(
    P8 P, const float* __restrict__ W1, const float* __restrict__ b1,
    const float* __restrict__ W2, const float* __restrict__ b2,
    float* __restrict__ out) {
    constexpr int K = 32 / CW;
    const int lane = threadIdx.x & 63;
    const int hh = lane >> 5;
    const int f = lane & 31;
    float w1r[3][32];
#pragma unroll
    for (int l = 0; l < 3; ++l)
#pragma unroll
        for (int g = 0; g < 32; ++g) w1r[l][g] = W1[(l * 32 + g) * 32 + f];
    const float w2a = W2[f], w2b = W2[32 + f], w2c = W2[64 + f];
    const float b1f = b1[f], b20 = b2[0];
    const int wv0 = (blockIdx.x * 256 + threadIdx.x) >> 6;
    const int nw = (gridDim.x * 256) >> 6;
    for (int ee = wv0; ee < E_EDGES; ee += nw) {
        const int e = __builtin_amdgcn_readfirstlane(ee);  // one edge per wave, uniform
        // x rows are wave-uniform -> scalar loads, FMA with SGPR operand
        float tA = b1f;
        float tc0 = 0.f, tc1 = 0.f, tc2 = 0.f, tc3 = 0.f;
#pragma unroll
        for (int rg = 0; rg < K; ++rg) {
            const float* xb = P.p[rg] + (size_t)e * 9 * CW;
#pragma unroll
            for (int gg = 0; gg < CW; ++gg)
                tA = fmaf(xb[gg], w1r[0][rg * CW + gg], tA);  // c=0, l=0
        }
        if (hh == 0) {  // c = 1..4  (l = 1,1,1,2)
#pragma unroll
            for (int rg = 0; rg < K; ++rg) {
                const float* xb = P.p[rg] + (size_t)e * 9 * CW;
#pragma unroll
                for (int gg = 0; gg < CW; ++gg) {
                    int g = rg * CW + gg;
                    tc0 = fmaf(xb[1 * CW + gg], w1r[1][g], tc0);
                    tc1 = fmaf(xb[2 * CW + gg], w1r[1][g], tc1);
                    tc2 = fmaf(xb[3 * CW + gg], w1r[1][g], tc2);
                    tc3 = fmaf(xb[4 * CW + gg], w1r[2][g], tc3);
                }
            }
        } else {  // c = 5..8  (all l = 2)
#pragma unroll
            for (int rg = 0; rg < K; ++rg) {
                const float* xb = P.p[rg] + (size_t)e * 9 * CW;
#pragma unroll
                for (int gg = 0; gg < CW; ++gg) {
                    int g = rg * CW + gg;
                    tc0 = fmaf(xb[5 * CW + gg], w1r[2][g], tc0);
                    tc1 = fmaf(xb[6 * CW + gg], w1r[2][g], tc1);
                    tc2 = fmaf(xb[7 * CW + gg], w1r[2][g], tc2);
                    tc3 = fmaf(xb[8 * CW + gg], w1r[2][g], tc3);
                }
            }
        }
        const bool gpos = tA > 0.f;
        const float wg0 = gpos ? w2a : 0.f;
        const float wg1 = gpos ? w2b : 0.f;
        const float wg2 = gpos ? w2c : 0.f;
        float r0 = hh ? tc0 * wg2 : tA * wg0;
        float r1 = hh ? tc1 * wg2 : tc0 * wg1;
        float r2 = hh ? tc2 * wg2 : tc1 * wg1;
        float r3 = hh ? tc3 * wg2 : tc2 * wg1;
        float r4 = hh ? 0.f : tc3 * wg2;
        r0 = red32(r0); r1 = red32(r1); r2 = red32(r2); r3 = red32(r3); r4 = red32(r4);
        if (lane == 31) {
            float* op = out + (size_t)e * 9;
            op[0] = r0 + b20; op[1] = r1; op[2] = r2; op[3] = r3; op[4] = r4;
        } else if (lane == 63) {
            float* op = out + (size_t)e * 9;
            op[5] = r0; op[6] = r1; op[7] = r2; op[8] = r3;
        }
    }
}

// ---------------- driver -------------------------------------------------------------
template <int CW>
static void run_all(const float* x_dftb, const float* coords, const int* dst,
                    const int* src, const float* W0, const float* b0,
                    const float* Wmp, const float* bmp, const float* W1,
                    const float* b1, const float* W2, const float* b2,
                    float* out, char* ws, hipStream_t stream) {
    constexpr int K = 32 / CW;
    size_t sliceB = (size_t)E_EDGES * 9 * CW * sizeof(float);
    float* G = (float*)ws;
    int* row_start = (int*)(ws + 4096);
    int* eidx = (int*)(ws + 4096 + 1 * 640 * 1024);
    int* cnt = (int*)(ws + 4096 + 2 * 640 * 1024);
    int* cursor = (int*)(ws + 4096 + 3 * 640 * 1024);
    int* perm = (int*)(ws + 4096 + 4 * 640 * 1024);
    int* bsum = (int*)(ws + 4096 + 5 * 640 * 1024);                   // 512 ints
    int* blockhist = (int*)(ws + 4096 + 5 * 640 * 1024 + 64 * 1024);  // 32*512 ints
    // coef table reuses cnt+cursor space (dead after sort3): 768*352*4 = 1056 KB
    float* tbl = (float*)(ws + 4096 + 2 * 640 * 1024);

    float* reg[K + 1];
    for (int i = 0; i <= K; ++i) reg[i] = (float*)(ws + REG_OFF + (size_t)i * sliceB);
    int cur[K];
    for (int i = 0; i < K; ++i) cur[i] = i;
    int spare = K;

    const int EB = E_EDGES / 256;  // 512
    gaunt_init<<<1, 256, 0, stream>>>(G);
    fill_int<<<EB, 256, 0, stream>>>(cnt, E_EDGES, 0);
    csr_count<<<EB, 256, 0, stream>>>(dst, cnt);
    csr_bsum<<<EB, 256, 0, stream>>>(cnt, bsum);
    scan512_wave<<<1, 64, 0, stream>>>(bsum);
    csr_row<<<EB, 256, 0, stream>>>(cnt, bsum, row_start, cursor);
    csr_scatter<<<EB, 256, 0, stream>>>(dst, cursor, eidx);
    sort1<<<EB, 256, 0, stream>>>(cnt, blockhist);
    sort2<<<1, 1024, 0, stream>>>(blockhist);
    sort3<<<EB, 256, 0, stream>>>(cnt, blockhist, perm);

    P8 Pe;
    for (int i = 0; i < 8; ++i) Pe.p[i] = reg[(i < K) ? cur[i] : 0];
    embed2<CW><<<E_EDGES / 8, 256, 0, stream>>>(x_dftb, W0, b0, Pe);

    const int mp_grid = (CW == 8) ? 1792 : 1024;
    for (int step = 0; step < 2; ++step) {
        build_tbl<<<TBL_N, 256, 0, stream>>>(Wmp + step * 27648, bmp + step * 864, tbl);
        for (int h = 0; h < K; ++h) {
            mp_pull3<CW><<<mp_grid, 256, 0, stream>>>(
                reg[cur[h]], reg[spare], coords, row_start, eidx, src, perm, tbl, G, h);
            int tmp = cur[h]; cur[h] = spare; spare = tmp;
        }
    }
    P8 Pf;
    for (int i = 0; i < 8; ++i) Pf.p[i] = reg[(i < K) ? cur[i] : 0];
    final6<CW><<<2048, 256, 0, stream>>>(Pf, W1, b1, W2, b2, out);
}

extern "C" void kernel_launch(void* const* d_in, const int* in_sizes, int n_in,
                              void* d_out, int out_size, void* d_ws, size_t ws_size,
                              hipStream_t stream) {
    const float* x_dftb = (const float*)d_in[0];
    const float* coords = (const float*)d_in[1];
    const int* dst = (const int*)d_in[2];
    const int* src = (const int*)d_in[3];
    const float* W0 = (const float*)d_in[4];
    const float* b0 = (const float*)d_in[5];
    const float* Wmp = (const float*)d_in[6];
    const float* bmp = (const float*)d_in[7];
    const float* W1 = (const float*)d_in[8];
    const float* b1 = (const float*)d_in[9];
    const float* W2 = (const float*)d_in[10];
    const float* b2 = (const float*)d_in[11];
    float* out = (float*)d_out;
    char* ws = (char*)d_ws;

    size_t slice8 = (size_t)E_EDGES * 9 * 8 * sizeof(float);
    size_t slice4 = (size_t)E_EDGES * 9 * 4 * sizeof(float);
    size_t need8 = REG_OFF + 5 * slice8;
    size_t need4 = REG_OFF + 9 * slice4;
    if (ws_size >= need8) {
        run_all<8>(x_dftb, coords, dst, src, W0, b0, Wmp, bmp, W1, b1, W2, b2, out, ws, stream);
    } else if (ws_size >= need4) {
        run_all<4>(x_dftb, coords, dst, src, W0, b0, Wmp, bmp, W1, b1, W2, b2, out, ws, stream);
    } else {
        zero_kernel<<<(out_size + 255) / 256, 256, 0, stream>>>(out, (size_t)out_size);
    }
}

// Round 9
// 976.285 us; speedup vs baseline: 3.1229x; 1.1717x over previous
//
#include <hip/hip_runtime.h>

#define E_EDGES 131072
#define FIN 16
#define FF 32
#define REG_OFF (4u << 20)  // 4 MB reserved: Gaunt + CSR + sort + coef-table arrays

// ---- combo tables: 11 allowed (l1,l2,l3); blocks l=0:[0,1) l=1:[1,4) l=2:[4,9) ----
constexpr int CIDX[11] = {0, 4, 8, 10, 12, 14, 16, 20, 22, 24, 26};
constexpr int CA0[11] = {0, 0, 0, 1, 1, 1, 1, 4, 4, 4, 4};
constexpr int CDA[11] = {1, 1, 1, 3, 3, 3, 3, 5, 5, 5, 5};
constexpr int CQ0[11] = {0, 1, 4, 0, 1, 1, 4, 0, 1, 4, 4};
constexpr int CC0[11] = {0, 1, 4, 1, 0, 4, 1, 4, 1, 0, 4};
constexpr int CDC[11] = {1, 3, 5, 3, 1, 5, 3, 5, 3, 1, 5};
constexpr int CL2[11] = {0, 1, 2, 0, 1, 1, 2, 0, 1, 2, 2};
constexpr int CZ0[11] = {0, 1, 4, 9, 18, 21, 36, 45, 70, 85, 90};    // unpadded cum, 115
constexpr int CZP[11] = {0, 4, 8, 16, 28, 32, 48, 60, 88, 104, 112}; // pad4 offsets, 140

#define TBL_N 768
#define TBL_RMAX 12.0
#define TBL_INVH ((float)(767.0 / 12.0))

struct P8 { float* p[8]; };

// ---------------- Gaunt tensor via exact quadrature (matches reference) -------------
__global__ void gaunt_init(float* __restrict__ G) {
    __shared__ double Ys[128][9];
    __shared__ double wq[128];
    const double ct[8] = {
        -0.9602898564975363, -0.7966664774136267, -0.5255324099163290, -0.1834346424956498,
         0.1834346424956498,  0.5255324099163290,  0.7966664774136267,  0.9602898564975363};
    const double wgt[8] = {
        0.1012285362903763, 0.2223810344533745, 0.3137066458778873, 0.3626837833783620,
        0.3626837833783620, 0.3137066458778873, 0.2223810344533745, 0.1012285362903763};
    const double PI = 3.141592653589793238462643383279502884;
    int t = threadIdx.x;
    if (t < 128) {
        int iq = t >> 4, ip = t & 15;
        double c = ct[iq];
        double s = sqrt(1.0 - c * c);
        double phi = (double)ip * (2.0 * PI / 16.0);
        double x = s * cos(phi), y = s * sin(phi), z = c;
        double* Yp = Ys[t];
        Yp[0] = 0.28209479177387814;
        Yp[1] = 0.4886025119029199 * y;
        Yp[2] = 0.4886025119029199 * z;
        Yp[3] = 0.4886025119029199 * x;
        Yp[4] = 1.0925484305920792 * x * y;
        Yp[5] = 1.0925484305920792 * y * z;
        Yp[6] = 0.31539156525252005 * (3.0 * z * z - 1.0);
        Yp[7] = 1.0925484305920792 * x * z;
        Yp[8] = 0.5462742152960396 * (x * x - y * y);
        wq[t] = wgt[iq] * (2.0 * PI / 16.0);
    }
    __syncthreads();
    for (int idx = t; idx < 729; idx += blockDim.x) {
        int a = idx / 81, b = (idx / 9) % 9, cc = idx % 9;
        double sum = 0.0;
        for (int q = 0; q < 128; ++q) sum += wq[q] * Ys[q][a] * Ys[q][b] * Ys[q][cc];
        G[idx] = (float)sum;
    }
}

// ---------------- small utility kernels ---------------------------------------------
__global__ __launch_bounds__(256) void zero_kernel(float* __restrict__ p, size_t n) {
    size_t i = (size_t)blockIdx.x * 256 + threadIdx.x;
    if (i < n) p[i] = 0.f;
}
__global__ __launch_bounds__(256) void fill_int(int* __restrict__ p, int n, int v) {
    int i = blockIdx.x * 256 + threadIdx.x;
    if (i < n) p[i] = v;
}

// ---------------- CSR build ----------------------------------------------------------
__global__ __launch_bounds__(256) void csr_count(const int* __restrict__ dst,
                                                 int* __restrict__ cnt) {
    int e = blockIdx.x * 256 + threadIdx.x;
    atomicAdd(&cnt[dst[e]], 1);  // 131072 spread addresses: low contention
}
__global__ __launch_bounds__(256) void csr_bsum(const int* __restrict__ cnt,
                                                int* __restrict__ bsum) {
    int i = blockIdx.x * 256 + threadIdx.x;
    int v = cnt[i];
#pragma unroll
    for (int off = 32; off; off >>= 1) v += __shfl_down(v, off, 64);
    __shared__ int w4[4];
    if ((threadIdx.x & 63) == 0) w4[threadIdx.x >> 6] = v;
    __syncthreads();
    if (threadIdx.x == 0) bsum[blockIdx.x] = w4[0] + w4[1] + w4[2] + w4[3];
}
__global__ void scan512_wave(int* __restrict__ b) {
    int lane = threadIdx.x;  // 64 threads
    int run = 0;
    for (int c = 0; c < 8; ++c) {
        int v = b[c * 64 + lane];
        int s = v;
#pragma unroll
        for (int off = 1; off < 64; off <<= 1) {
            int t = __shfl_up(s, off, 64);
            if (lane >= off) s += t;
        }
        b[c * 64 + lane] = run + s - v;
        run += __shfl(s, 63, 64);
    }
}
__global__ __launch_bounds__(256) void csr_row(const int* __restrict__ cnt,
                                               const int* __restrict__ bsum,
                                               int* __restrict__ row_start,
                                               int* __restrict__ cursor) {
    __shared__ int sd[256];
    const int i = blockIdx.x * 256 + threadIdx.x;
    const int my = cnt[i];
    sd[threadIdx.x] = my;
    __syncthreads();
    for (int off = 1; off < 256; off <<= 1) {
        int t = (threadIdx.x >= off) ? sd[threadIdx.x - off] : 0;
        __syncthreads();
        sd[threadIdx.x] += t;
        __syncthreads();
    }
    int rs = bsum[blockIdx.x] + sd[threadIdx.x] - my;
    row_start[i] = rs;
    cursor[i] = rs;
    if (blockIdx.x == 511 && threadIdx.x == 255)
        row_start[E_EDGES] = bsum[511] + sd[255];
}
__global__ __launch_bounds__(256) void csr_scatter(const int* __restrict__ dst,
                                                   int* __restrict__ cursor,
                                                   int* __restrict__ eidx) {
    int e = blockIdx.x * 256 + threadIdx.x;
    int pos = atomicAdd(&cursor[dst[e]], 1);  // spread addresses: fine
    eidx[pos] = e;
}

// ---------------- degree counting-sort (no contended global atomics) ----------------
__global__ __launch_bounds__(256) void sort1(const int* __restrict__ cnt,
                                             int* __restrict__ blockhist) {
    __shared__ int h[32];
    if (threadIdx.x < 32) h[threadIdx.x] = 0;
    __syncthreads();
    int n = blockIdx.x * 256 + threadIdx.x;
    int d = cnt[n]; if (d > 31) d = 31;
    atomicAdd(&h[d], 1);  // LDS atomic, cheap
    __syncthreads();
    if (threadIdx.x < 32) blockhist[threadIdx.x * 512 + blockIdx.x] = h[threadIdx.x];
}
__global__ __launch_bounds__(1024) void sort2(int* __restrict__ blockhist) {
    __shared__ int tot[32];
    int wv = threadIdx.x >> 6, lane = threadIdx.x & 63;  // 16 waves, 2 bins each
#pragma unroll
    for (int bi = 0; bi < 2; ++bi) {
        int bin = wv * 2 + bi;
        int run = 0;
        for (int c = 0; c < 8; ++c) {
            int v = blockhist[bin * 512 + c * 64 + lane];
            int s = v;
#pragma unroll
            for (int off = 1; off < 64; off <<= 1) {
                int t = __shfl_up(s, off, 64);
                if (lane >= off) s += t;
            }
            blockhist[bin * 512 + c * 64 + lane] = run + s - v;
            run += __shfl(s, 63, 64);
        }
        if (lane == 0) tot[bin] = run;
    }
    __syncthreads();
    if (threadIdx.x == 0) {
        int run = 0;
        for (int i = 0; i < 32; ++i) { int t = tot[i]; tot[i] = run; run += t; }
    }
    __syncthreads();
#pragma unroll
    for (int bi = 0; bi < 2; ++bi) {
        int bin = wv * 2 + bi;
        int base = tot[bin];
        for (int c = 0; c < 8; ++c) blockhist[bin * 512 + c * 64 + lane] += base;
    }
}
__global__ __launch_bounds__(256) void sort3(const int* __restrict__ cnt,
                                             const int* __restrict__ blockhist,
                                             int* __restrict__ perm) {
    __shared__ int cur[32];
    if (threadIdx.x < 32) cur[threadIdx.x] = blockhist[threadIdx.x * 512 + blockIdx.x];
    __syncthreads();
    int n = blockIdx.x * 256 + threadIdx.x;
    int d = cnt[n]; if (d > 31) d = 31;
    int pos = atomicAdd(&cur[d], 1);  // LDS atomic, cheap
    perm[pos] = n;
}

// ---------------- coef lookup table: T[u][k][f] = bm + rad(u*h) @ W -----------------
__global__ __launch_bounds__(256) void build_tbl(const float* __restrict__ Wm,
                                                 const float* __restrict__ bm,
                                                 float* __restrict__ tbl) {
    __shared__ float rad[32];
    const int u = blockIdx.x;
    const int tid = threadIdx.x;
    if (tid < 32) {
        double r = (double)u * (TBL_RMAX / (double)(TBL_N - 1));
        double c = (double)tid * (4.0 / 31.0);
        double d = r - c;
        rad[tid] = (float)exp(-d * d);
    }
    __syncthreads();
    for (int i = tid; i < 352; i += 256) {
        int k = i >> 5, f = i & 31;
        float acc = bm[CIDX[k] * 32 + f];
        const float* W = Wm + CIDX[k] * 1024 + f;
#pragma unroll
        for (int b = 0; b < 32; ++b) acc = fmaf(rad[b], W[b * 32], acc);
        tbl[(size_t)u * 352 + i] = acc;
    }
}

// ---------------- embed: (E,9,16)@(16->32) into chunk-major regions ------------------
template <int CW>
__global__ __launch_bounds__(256) void embed2(
    const float* __restrict__ xin, const float* __restrict__ W0,
    const float* __restrict__ b0, P8 P) {
    constexpr int K = 32 / CW;
    int tid = threadIdx.x;
    int e = blockIdx.x * 8 + (tid >> 5);
    int f = tid & 31;
    int h = f / CW, fc = f % CW;
    float* Rh = P.p[0];
#pragma unroll
    for (int i = 1; i < K; ++i) Rh = (h == i) ? P.p[i] : Rh;
    const float* xr = xin + (size_t)e * 144;
#pragma unroll
    for (int c = 0; c < 9; ++c) {
        int l = (c == 0) ? 0 : ((c < 4) ? 1 : 2);
        const float* Wl = W0 + l * FIN * FF;
        float acc = (c == 0) ? b0[f] : 0.f;
#pragma unroll
        for (int q = 0; q < 4; ++q) {
            float4 xv = *(const float4*)&xr[c * 16 + q * 4];
            acc = fmaf(xv.x, Wl[(q * 4 + 0) * 32 + f], acc);
            acc = fmaf(xv.y, Wl[(q * 4 + 1) * 32 + f], acc);
            acc = fmaf(xv.z, Wl[(q * 4 + 2) * 32 + f], acc);
            acc = fmaf(xv.w, Wl[(q * 4 + 3) * 32 + f], acc);
        }
        Rh[((size_t)e * 9 + c) * CW + fc] = acc;
    }
}

// ---------------- per-combo einsum piece (all compile-time indexed) -----------------
template <int K>
__device__ __forceinline__ void comboP(const float* __restrict__ zrow,
                                       const float (&coef)[11], const float (&xa)[9],
                                       float (&acc)[9]) {
    constexpr int A0 = CA0[K], DA = CDA[K], C0 = CC0[K], DC = CDC[K];
    constexpr int SZ = DA * DC, N4 = (SZ + 3) / 4, ZP = CZP[K];
    float zz[N4 * 4];
    const float4* zp = (const float4*)(zrow + ZP);
#pragma unroll
    for (int j = 0; j < N4; ++j) {
        float4 v = zp[j];
        zz[4 * j + 0] = v.x; zz[4 * j + 1] = v.y; zz[4 * j + 2] = v.z; zz[4 * j + 3] = v.w;
    }
    float m[DC] = {};
#pragma unroll
    for (int a = 0; a < DA; ++a)
#pragma unroll
        for (int c = 0; c < DC; ++c) m[c] = fmaf(xa[A0 + a], zz[a * DC + c], m[c]);
#pragma unroll
    for (int c = 0; c < DC; ++c) acc[C0 + c] = fmaf(coef[K], m[c], acc[C0 + c]);
}

// ---------------- message pass, CSR pull, chunk h, table coef -----------------------
template <int CW>
__global__ __launch_bounds__(256) void mp_pull3(
    const float* __restrict__ Xold, float* __restrict__ Xnew,
    const float* __restrict__ coords,
    const int* __restrict__ row_start, const int* __restrict__ eidx,
    const int* __restrict__ src, const int* __restrict__ perm,
    const float* __restrict__ tbl, const float* __restrict__ Gglob, int h) {
    constexpr int EPB = 256 / CW;
    constexpr int NB_TOT = E_EDGES / EPB;
    __shared__ float gG[729];
    __shared__ int tab[115];
    __shared__ float z_s[EPB * 140];
    const int tid = threadIdx.x;
    for (int i = tid; i < 729; i += 256) gG[i] = Gglob[i];
    for (int t = tid; t < 115; t += 256) {
        int k = 0;
#pragma unroll
        for (int kk = 1; kk < 11; ++kk) if (t >= CZ0[kk]) k = kk;
        int loc = t - CZ0[k];
        int dc = CDC[k];
        int a = loc / dc, c = loc - a * dc;
        int base = (CA0[k] + a) * 81 + CQ0[k] * 9 + (CC0[k] + c);
        tab[t] = ((CZP[k] + loc) << 12) | (CL2[k] << 10) | base;
    }
    __syncthreads();

    const int g = tid / CW, fc = tid % CW;
    const int f = h * CW + fc;
    float* zrow = &z_s[g * 140];

    for (int nb = blockIdx.x; nb < NB_TOT; nb += gridDim.x) {
        const int d = perm[nb * EPB + g];
        const int r0 = row_start[d], r1 = row_start[d + 1];
        float acc[9];
#pragma unroll
        for (int a = 0; a < 9; ++a) acc[a] = Xold[((size_t)d * 9 + a) * CW + fc];
        const float ddx = coords[3 * d], ddy = coords[3 * d + 1], ddz = coords[3 * d + 2];

        // 1-deep software pipeline over the row's edges
        int ps = 0; float pcx = 0.f, pcy = 0.f, pcz = 0.f;
        float pxa[9];
        if (r0 < r1) {
            int pe = eidx[r0]; ps = src[pe];
            pcx = coords[3 * ps]; pcy = coords[3 * ps + 1]; pcz = coords[3 * ps + 2];
#pragma unroll
            for (int a = 0; a < 9; ++a) pxa[a] = Xold[((size_t)ps * 9 + a) * CW + fc];
        }
        for (int p = r0; p < r1; ++p) {
            const float rx = ddx - pcx, ry = ddy - pcy, rz = ddz - pcz;
            float xa[9];
#pragma unroll
            for (int a = 0; a < 9; ++a) xa[a] = pxa[a];
            if (p + 1 < r1) {  // prefetch next edge under this edge's compute
                int pe = eidx[p + 1]; ps = src[pe];
                pcx = coords[3 * ps]; pcy = coords[3 * ps + 1]; pcz = coords[3 * ps + 2];
#pragma unroll
                for (int a = 0; a < 9; ++a) pxa[a] = Xold[((size_t)ps * 9 + a) * CW + fc];
            }
            float r = sqrtf(rx * rx + ry * ry + rz * rz + 1e-8f);
            float inv = 1.f / r;
            float ux = rx * inv, uy = ry * inv, uz = rz * inv;
            float y9[9];
            y9[0] = 0.28209479177387814f;
            y9[1] = 0.4886025119029199f * uy; y9[2] = 0.4886025119029199f * uz;
            y9[3] = 0.4886025119029199f * ux;
            y9[4] = 1.0925484305920792f * ux * uy; y9[5] = 1.0925484305920792f * uy * uz;
            y9[6] = 0.31539156525252005f * (3.f * uz * uz - 1.f);
            y9[7] = 1.0925484305920792f * ux * uz;
            y9[8] = 0.5462742152960396f * (ux * ux - uy * uy);
            // coef via cubic Lagrange interp of T[u][k][f]  (replaces rad@W GEMM)
            float rt = r * TBL_INVH;
            int u = (int)rt;
            u = (u < 1) ? 1 : ((u > TBL_N - 3) ? (TBL_N - 3) : u);
            float w = rt - (float)u;
            float wp1 = w + 1.f, wm1 = w - 1.f, wm2 = w - 2.f;
            float lm = -w * wm1 * wm2 * (1.f / 6.f);
            float l0 = wp1 * wm1 * wm2 * 0.5f;
            float l1 = -wp1 * w * wm2 * 0.5f;
            float l2 = wp1 * w * wm1 * (1.f / 6.f);
            const float* tb = tbl + (size_t)(u - 1) * 352 + f;
            float coef[11];
#pragma unroll
            for (int k = 0; k < 11; ++k) {
                const float* tk = tb + k * 32;
                float cc = lm * tk[0];
                cc = fmaf(l0, tk[352], cc);
                cc = fmaf(l1, tk[704], cc);
                cc = fmaf(l2, tk[1056], cc);
                coef[k] = cc;
            }
            // z[t] = sum_b Y[Q0+b] * G[base + 9b], distributed over group, LDS-shared
            for (int t = fc; t < 115; t += CW) {
                int u2 = tab[t];
                int base = u2 & 0x3FF;
                int l2u = (u2 >> 10) & 3;
                float zv;
                if (l2u == 0) {
                    zv = y9[0] * gG[base];
                } else if (l2u == 1) {
                    zv = y9[1] * gG[base];
                    zv = fmaf(y9[2], gG[base + 9], zv);
                    zv = fmaf(y9[3], gG[base + 18], zv);
                } else {
                    zv = y9[4] * gG[base];
                    zv = fmaf(y9[5], gG[base + 9], zv);
                    zv = fmaf(y9[6], gG[base + 18], zv);
                    zv = fmaf(y9[7], gG[base + 27], zv);
                    zv = fmaf(y9[8], gG[base + 36], zv);
                }
                zrow[u2 >> 12] = zv;
            }
            asm volatile("s_waitcnt lgkmcnt(0)" ::: "memory");
            comboP<0>(zrow, coef, xa, acc);
            comboP<1>(zrow, coef, xa, acc);
            comboP<2>(zrow, coef, xa, acc);
            comboP<3>(zrow, coef, xa, acc);
            comboP<4>(zrow, coef, xa, acc);
            comboP<5>(zrow, coef, xa, acc);
            comboP<6>(zrow, coef, xa, acc);
            comboP<7>(zrow, coef, xa, acc);
            comboP<8>(zrow, coef, xa, acc);
            comboP<9>(zrow, coef, xa, acc);
            comboP<10>(zrow, coef, xa, acc);
        }
#pragma unroll
        for (int a = 0; a < 9; ++a) Xnew[((size_t)d * 9 + a) * CW + fc] = acc[a];
    }
}

// ---------------- DPP helpers --------------------------------------------------------
template <int CTRL>
__device__ __forceinline__ float dpp_add(float v) {
    int t = __builtin_amdgcn_update_dpp(0, __builtin_bit_cast(int, v),
                                        CTRL, 0xF, 0xF, true);
    return v + __builtin_bit_cast(float, t);
}
// sum within each 8-lane group; result valid in lane 7 of each group
__device__ __forceinline__ float red8(float v) {
    v = dpp_add<0x111>(v);  // row_shr:1
    v = dpp_add<0x112>(v);  // row_shr:2
    v = dpp_add<0x114>(v);  // row_shr:4
    return v;
}

// ---------------- final7: wave = 8 edges x 8 f-quads; W1 in LDS; x direct global ----
template <int CW>
__global__ __launch_bounds__(256) void final7(
    P8 P, const float* __restrict__ W1, const float* __restrict__ b1,
    const float* __restrict__ W2, const float* __restrict__ b2,
    float* __restrict__ out) {
    __shared__ float W_s[3 * 32 * 32];  // 12 KB, same layout as W1
    const int tid = threadIdx.x;
    for (int i = tid; i < 3072; i += 256) W_s[i] = W1[i];
    __syncthreads();

    const int lane = tid & 63;
    const int e_sub = lane >> 3;   // 8 edges per wave
    const int fq = lane & 7;       // 8 f-quads, f = fq*4 .. fq*4+3
    // per-lane W2 columns (3 l-classes x 4 f)
    float w2r[3][4];
#pragma unroll
    for (int l = 0; l < 3; ++l)
#pragma unroll
        for (int j = 0; j < 4; ++j) w2r[l][j] = W2[l * 32 + fq * 4 + j];
    float b1r[4];
#pragma unroll
    for (int j = 0; j < 4; ++j) b1r[j] = b1[fq * 4 + j];
    const float b20 = b2[0];

    const int wv = (blockIdx.x * 256 + tid) >> 6;
    const int nw = (gridDim.x * 256) >> 6;
    constexpr int NG = E_EDGES / 8;

    for (int gp = wv; gp < NG; gp += nw) {
        const size_t e = (size_t)gp * 8 + e_sub;
        float t[9][4];
#pragma unroll
        for (int j = 0; j < 4; ++j) t[0][j] = b1r[j];
#pragma unroll
        for (int c = 1; c < 9; ++c)
#pragma unroll
            for (int j = 0; j < 4; ++j) t[c][j] = 0.f;

#pragma unroll
        for (int gq = 0; gq < 8; ++gq) {   // g-quad: g = 4*gq .. 4*gq+3
            const int h = (gq * 4) / CW;
            const int off = (gq * 4) % CW;
            const float* xb = P.p[h] + (e * 9) * CW + off;
            // W quads for the 3 l-classes (LDS broadcast, conflict-free 128B rows)
            float wq[3][4][4];
#pragma unroll
            for (int l = 0; l < 3; ++l)
#pragma unroll
                for (int gi = 0; gi < 4; ++gi) {
                    float4 wv4 = *(const float4*)&W_s[(l * 32 + gq * 4 + gi) * 32 + fq * 4];
                    wq[l][gi][0] = wv4.x; wq[l][gi][1] = wv4.y;
                    wq[l][gi][2] = wv4.z; wq[l][gi][3] = wv4.w;
                }
            // x quads (global, 8-lane dedup -> coalesced 128B/instr)
            float xq[9][4];
#pragma unroll
            for (int c = 0; c < 9; ++c) {
                float4 xv = *(const float4*)&xb[c * CW];
                xq[c][0] = xv.x; xq[c][1] = xv.y; xq[c][2] = xv.z; xq[c][3] = xv.w;
            }
#pragma unroll
            for (int c = 0; c < 9; ++c) {
                const int l = (c == 0) ? 0 : ((c < 4) ? 1 : 2);
#pragma unroll
                for (int gi = 0; gi < 4; ++gi)
#pragma unroll
                    for (int j = 0; j < 4; ++j)
                        t[c][j] = fmaf(xq[c][gi], wq[l][gi][j], t[c][j]);
            }
        }
        // gate per (e, f): sign of scalar channel
        float gw[3][4];
#pragma unroll
        for (int j = 0; j < 4; ++j) {
            const float gate = (t[0][j] > 0.f) ? 1.f : 0.f;
#pragma unroll
            for (int l = 0; l < 3; ++l) gw[l][j] = gate * w2r[l][j];
        }
#pragma unroll
        for (int c = 0; c < 9; ++c) {
            const int l = (c == 0) ? 0 : ((c < 4) ? 1 : 2);
            float v = t[c][0] * gw[l][0];
            v = fmaf(t[c][1], gw[l][1], v);
            v = fmaf(t[c][2], gw[l][2], v);
            v = fmaf(t[c][3], gw[l][3], v);
            v = red8(v);
            if (fq == 7) out[e * 9 + c] = v + ((c == 0) ? b20 : 0.f);
        }
    }
}

// ---------------- driver -------------------------------------------------------------
template <int CW>
static void run_all(const float* x_dftb, const float* coords, const int* dst,
                    const int* src, const float* W0, const float* b0,
                    const float* Wmp, const float* bmp, const float* W1,
                    const float* b1, const float* W2, const float* b2,
                    float* out, char* ws, hipStream_t stream) {
    constexpr int K = 32 / CW;
    size_t sliceB = (size_t)E_EDGES * 9 * CW * sizeof(float);
    float* G = (float*)ws;
    int* row_start = (int*)(ws + 4096);
    int* eidx = (int*)(ws + 4096 + 1 * 640 * 1024);
    int* cnt = (int*)(ws + 4096 + 2 * 640 * 1024);
    int* cursor = (int*)(ws + 4096 + 3 * 640 * 1024);
    int* perm = (int*)(ws + 4096 + 4 * 640 * 1024);
    int* bsum = (int*)(ws + 4096 + 5 * 640 * 1024);                   // 512 ints
    int* blockhist = (int*)(ws + 4096 + 5 * 640 * 1024 + 64 * 1024);  // 32*512 ints
    // coef table reuses cnt+cursor space (dead after sort3): 768*352*4 = 1056 KB
    float* tbl = (float*)(ws + 4096 + 2 * 640 * 1024);

    float* reg[K + 1];
    for (int i = 0; i <= K; ++i) reg[i] = (float*)(ws + REG_OFF + (size_t)i * sliceB);
    int cur[K];
    for (int i = 0; i < K; ++i) cur[i] = i;
    int spare = K;

    const int EB = E_EDGES / 256;  // 512
    gaunt_init<<<1, 256, 0, stream>>>(G);
    fill_int<<<EB, 256, 0, stream>>>(cnt, E_EDGES, 0);
    csr_count<<<EB, 256, 0, stream>>>(dst, cnt);
    csr_bsum<<<EB, 256, 0, stream>>>(cnt, bsum);
    scan512_wave<<<1, 64, 0, stream>>>(bsum);
    csr_row<<<EB, 256, 0, stream>>>(cnt, bsum, row_start, cursor);
    csr_scatter<<<EB, 256, 0, stream>>>(dst, cursor, eidx);
    sort1<<<EB, 256, 0, stream>>>(cnt, blockhist);
    sort2<<<1, 1024, 0, stream>>>(blockhist);
    sort3<<<EB, 256, 0, stream>>>(cnt, blockhist, perm);

    P8 Pe;
    for (int i = 0; i < 8; ++i) Pe.p[i] = reg[(i < K) ? cur[i] : 0];
    embed2<CW><<<E_EDGES / 8, 256, 0, stream>>>(x_dftb, W0, b0, Pe);

    const int mp_grid = (CW == 8) ? 1792 : 1024;
    for (int step = 0; step < 2; ++step) {
        build_tbl<<<TBL_N, 256, 0, stream>>>(Wmp + step * 27648, bmp + step * 864, tbl);
        for (int h = 0; h < K; ++h) {
            mp_pull3<CW><<<mp_grid, 256, 0, stream>>>(
                reg[cur[h]], reg[spare], coords, row_start, eidx, src, perm, tbl, G, h);
            int tmp = cur[h]; cur[h] = spare; spare = tmp;
        }
    }
    P8 Pf;
    for (int i = 0; i < 8; ++i) Pf.p[i] = reg[(i < K) ? cur[i] : 0];
    final7<CW><<<2048, 256, 0, stream>>>(Pf, W1, b1, W2, b2, out);
}

extern "C" void kernel_launch(void* const* d_in, const int* in_sizes, int n_in,
                              void* d_out, int out_size, void* d_ws, size_t ws_size,
                              hipStream_t stream) {
    const float* x_dftb = (const float*)d_in[0];
    const float* coords = (const float*)d_in[1];
    const int* dst = (const int*)d_in[2];
    const int* src = (const int*)d_in[3];
    const float* W0 = (const float*)d_in[4];
    const float* b0 = (const float*)d_in[5];
    const float* Wmp = (const float*)d_in[6];
    const float* bmp = (const float*)d_in[7];
    const float* W1 = (const float*)d_in[8];
    const float* b1 = (const float*)d_in[9];
    const float* W2 = (const float*)d_in[10];
    const float* b2 = (const float*)d_in[11];
    float* out = (float*)d_out;
    char* ws = (char*)d_ws;

    size_t slice8 = (size_t)E_EDGES * 9 * 8 * sizeof(float);
    size_t slice4 = (size_t)E_EDGES * 9 * 4 * sizeof(float);
    size_t need8 = REG_OFF + 5 * slice8;
    size_t need4 = REG_OFF + 9 * slice4;
    if (ws_size >= need8) {
        run_all<8>(x_dftb, coords, dst, src, W0, b0, Wmp, bmp, W1, b1, W2, b2, out, ws, stream);
    } else if (ws_size >= need4) {
        run_all<4>(x_dftb, coords, dst, src, W0, b0, Wmp, bmp, W1, b1, W2, b2, out, ws, stream);
    } else {
        zero_kernel<<<(out_size + 255) / 256, 256, 0, stream>>>(out, (size_t)out_size);
    }
}